// Round 4
// baseline (97.960 us; speedup 1.0000x reference)
//
#include <hip/hip_runtime.h>

// LinearAttention on MI355X (gfx950) — R4.
// R4 vs R3: k2_fused restructured to eliminate barrier/latency serialization:
//   - px-tile 64, x-tile staged in LDS ONCE (was re-staged 3x for q/k/v)
//   - W A-fragments read directly from global (L1/L2-hot, 197 KB total)
//   - wave = head: q-softmax fully in-register (shfl), k/v via per-wave
//     padded LDS tiles (pitch 176 B), ctx MFMA per-wave, ~5 barriers/block
// Workspace:
//   W16   fp16[384*256]        @ 0
//   x_t   fp16[16][4096][256]  @ 196608
//   qhat  fp16[16][4096][128]  @ 33751040
//   ctx   f32 [16][4][32][32]  @ 50528256
//   sume  f32 [16][128]        @ 50790400
//   M     fp16[16][256][128]   @ 50798592
//   Wo16  fp16[256*128]        @ 51847168  (ends 51912704)

typedef _Float16 half8 __attribute__((ext_vector_type(8)));
typedef _Float16 half4 __attribute__((ext_vector_type(4)));
typedef float f32x4 __attribute__((ext_vector_type(4)));

#define SCALE_F 0.17677669529663687f

#define GLOAD16(g, s) __builtin_amdgcn_global_load_lds( \
    (const __attribute__((address_space(1))) void*)(g), \
    (__attribute__((address_space(3))) void*)(s), 16, 0, 0)

// ---------------- k1: rmsnorm-fold + transpose x -> x_t fp16 [b][p][c];
// x==64: convert W_qkv + W_out to fp16; x==65: zero ctx+sume. ----
__global__ __launch_bounds__(256) void k1_prep(const float* __restrict__ x,
                                               const float* __restrict__ g_norm,
                                               const float* __restrict__ W_qkv,
                                               const float* __restrict__ W_out,
                                               _Float16* __restrict__ W16,
                                               _Float16* __restrict__ Wo16,
                                               float* __restrict__ zbase,
                                               _Float16* __restrict__ x_t) {
  const int t = threadIdx.x;
  if (blockIdx.x == 64) {              // W conversion: 16 blocks x 256 thr x 8
    #pragma unroll
    for (int i = 0; i < 8; ++i) {
      int idx = blockIdx.y * 2048 + i * 256 + t;   // 32768 f32x4 chunks
      f32x4 v;
      if (idx < 24576) v = *(const f32x4*)(W_qkv + (size_t)idx * 4);
      else             v = *(const f32x4*)(W_out + (size_t)(idx - 24576) * 4);
      half4 h = {(_Float16)v[0], (_Float16)v[1], (_Float16)v[2], (_Float16)v[3]};
      if (idx < 24576) *(half4*)(W16 + (size_t)idx * 4) = h;
      else             *(half4*)(Wo16 + (size_t)(idx - 24576) * 4) = h;
    }
    return;
  }
  if (blockIdx.x == 65) {              // zero ctx (256K) + sume (8K)
    const f32x4 fz = {0.f, 0.f, 0.f, 0.f};
    float* zb = zbase + blockIdx.y * 4224;
    for (int off = t * 4; off < 4224; off += 1024)
      *(f32x4*)(zb + off) = fz;
    return;
  }
  const int b = blockIdx.y;
  const int p0 = blockIdx.x * 64;
  __shared__ _Float16 tile[256][68];   // [ch][px]
  __shared__ float g16s[256];
  __shared__ float psum[64][4];
  __shared__ float sinv[64];
  g16s[t] = g_norm[t] * 16.0f;
  const float* xb = x + (size_t)b * 256 * 4096;
  #pragma unroll
  for (int it = 0; it < 16; ++it) {
    int c = it * 16 + (t >> 4);
    int px = (t & 15) * 4;
    f32x4 v = *(const f32x4*)(xb + (size_t)c * 4096 + p0 + px);
    half4 h = {(_Float16)v[0], (_Float16)v[1], (_Float16)v[2], (_Float16)v[3]};
    *(half4*)&tile[c][px] = h;
  }
  __syncthreads();
  {
    int px = t & 63, q = t >> 6;
    float s = 0.f;
    #pragma unroll
    for (int i = 0; i < 64; ++i) {
      float f = (float)tile[q * 64 + i][px];
      s += f * f;
    }
    psum[px][q] = s;
  }
  __syncthreads();
  if (t < 64) {
    float s = psum[t][0] + psum[t][1] + psum[t][2] + psum[t][3];
    sinv[t] = rsqrtf(s + 1e-12f);
  }
  __syncthreads();
  _Float16* xt = x_t + ((size_t)b * 4096 + p0) * 256;
  #pragma unroll
  for (int j = 0; j < 8; ++j) {
    int idx8 = t + 256 * j;
    int px = idx8 >> 5;
    int c8 = (idx8 & 31) * 8;
    float iv = sinv[px];
    half8 h;
    #pragma unroll
    for (int i = 0; i < 8; ++i)
      h[i] = (_Float16)((float)tile[c8 + i][px] * iv * g16s[c8 + i]);
    *(half8*)(xt + (size_t)px * 256 + c8) = h;
  }
}

// ---------------- k2_fused (R4): one x-stage, W-from-global, wave=head ----
__global__ __launch_bounds__(256, 2) void k2_fused(const _Float16* __restrict__ W16,
                                                   const _Float16* __restrict__ x_t,
                                                   _Float16* __restrict__ qhat,
                                                   float* __restrict__ ctx,
                                                   float* __restrict__ sumexp) {
  const int pt = blockIdx.x, b = blockIdx.y;
  const int p0 = pt * 64;
  const int t = threadIdx.x;
  const int w = t >> 6, l = t & 63;
  const int lg = l >> 4, ll = l & 15;
  __shared__ __align__(1024) char smem[77824];
  // [0,32768): xbuf [64 px][512 B], 16B-chunk-swizzled (c ^= px&15)
  // [32768,55296): wt per-wave k-exp tile [32 ch][pitch 176 B]
  // [55296,77824): vt per-wave v tile (same pitch) / qt qtile [64 px][40 h]
  char* xbuf = smem;
  char* wt = smem + 32768 + w * 5632;
  char* vt = smem + 55296 + w * 5632;
  _Float16* qt = (_Float16*)(smem + 55296 + w * 5632);

  const _Float16* Xbase = x_t + ((size_t)b * 4096 + p0) * 256;
  // ---- stage x-tile once: 2048 x 16B chunks, pre-swizzled source ----
  #pragma unroll
  for (int i = 0; i < 8; ++i) {
    int q = (w * 8 + i) * 64 + l;          // chunk id 0..2047
    int px = q >> 5, c = q & 31;
    int cs = c ^ (px & 15);
    GLOAD16(Xbase + (size_t)px * 256 + cs * 8, smem + (w * 8 + i) * 1024);
  }
  __syncthreads();

  const f32x4 fz = {0.f, 0.f, 0.f, 0.f};
  #pragma unroll
  for (int mt = 0; mt < 3; ++mt) {
    f32x4 acc[2][4];
    #pragma unroll
    for (int i = 0; i < 2; ++i)
      #pragma unroll
      for (int j = 0; j < 4; ++j) acc[i][j] = fz;
    const _Float16* Wb = W16 + (size_t)(mt * 128 + w * 32) * 256;
    #pragma unroll
    for (int ks = 0; ks < 8; ++ks) {       // K = 8 x 32
      half8 af[2], bf[4];
      #pragma unroll
      for (int mf = 0; mf < 2; ++mf)
        af[mf] = *(const half8*)(Wb + (size_t)(mf * 16 + ll) * 256 + ks * 32 + lg * 8);
      #pragma unroll
      for (int nf = 0; nf < 4; ++nf) {
        int px = nf * 16 + ll;
        int c = (ks * 4 + lg) ^ (px & 15);
        bf[nf] = *(const half8*)(xbuf + px * 512 + c * 16);
      }
      #pragma unroll
      for (int mf = 0; mf < 2; ++mf)
        #pragma unroll
        for (int nf = 0; nf < 4; ++nf)
          acc[mf][nf] = __builtin_amdgcn_mfma_f32_16x16x32_f16(af[mf], bf[nf], acc[mf][nf], 0, 0, 0);
    }
    // acc val at (row = mf*16 + lg*4 + rr  [head-ch], col px = nf*16 + ll)
    if (mt == 0) {
      // q-softmax over head's 32 ch per px, fully in-register
      float e[2][4][4];
      float s[4] = {0.f, 0.f, 0.f, 0.f};
      #pragma unroll
      for (int mf = 0; mf < 2; ++mf)
        #pragma unroll
        for (int nf = 0; nf < 4; ++nf)
          #pragma unroll
          for (int rr = 0; rr < 4; ++rr) {
            float v = __expf(acc[mf][nf][rr]);
            e[mf][nf][rr] = v;
            s[nf] += v;
          }
      #pragma unroll
      for (int nf = 0; nf < 4; ++nf) {
        s[nf] += __shfl_xor(s[nf], 16);
        s[nf] += __shfl_xor(s[nf], 32);
        s[nf] = 1.0f / s[nf];
      }
      #pragma unroll
      for (int mf = 0; mf < 2; ++mf)
        #pragma unroll
        for (int nf = 0; nf < 4; ++nf) {
          half4 h;
          #pragma unroll
          for (int rr = 0; rr < 4; ++rr) h[rr] = (_Float16)(e[mf][nf][rr] * s[nf]);
          *(half4*)(qt + (nf * 16 + ll) * 40 + mf * 16 + lg * 4) = h;
        }
      __syncthreads();
      // coalesced qhat store: lanes 0-3 cover one px row's 64 B (head w)
      #pragma unroll
      for (int i = 0; i < 4; ++i) {
        int q = i * 64 + l;
        int px = q >> 2, c8 = (q & 3) * 8;
        half8 h = *(const half8*)(qt + px * 40 + c8);
        *(half8*)(qhat + ((size_t)b * 4096 + p0 + px) * 128 + w * 32 + c8) = h;
      }
    } else if (mt == 1) {
      // k: e = exp(logit-10); row-sums -> sume atomics; scatter -> wt[ch][px]
      float e[2][4][4];
      float rs[2][4];
      #pragma unroll
      for (int mf = 0; mf < 2; ++mf)
        #pragma unroll
        for (int rr = 0; rr < 4; ++rr) rs[mf][rr] = 0.f;
      #pragma unroll
      for (int mf = 0; mf < 2; ++mf)
        #pragma unroll
        for (int nf = 0; nf < 4; ++nf)
          #pragma unroll
          for (int rr = 0; rr < 4; ++rr) {
            float v = __expf(acc[mf][nf][rr] - 10.f);
            e[mf][nf][rr] = v;
            rs[mf][rr] += v;
          }
      #pragma unroll
      for (int mf = 0; mf < 2; ++mf)
        #pragma unroll
        for (int rr = 0; rr < 4; ++rr) {
          float v = rs[mf][rr];
          v += __shfl_xor(v, 1);
          v += __shfl_xor(v, 2);
          v += __shfl_xor(v, 4);
          v += __shfl_xor(v, 8);
          rs[mf][rr] = v;
        }
      if (ll == 0) {
        #pragma unroll
        for (int mf = 0; mf < 2; ++mf)
          #pragma unroll
          for (int rr = 0; rr < 4; ++rr)
            atomicAdd(&sumexp[b * 128 + w * 32 + mf * 16 + lg * 4 + rr], rs[mf][rr]);
      }
      #pragma unroll
      for (int mf = 0; mf < 2; ++mf)
        #pragma unroll
        for (int nf = 0; nf < 4; ++nf)
          #pragma unroll
          for (int rr = 0; rr < 4; ++rr)
            *(_Float16*)(wt + (mf * 16 + lg * 4 + rr) * 176 + (nf * 16 + ll) * 2) =
                (_Float16)e[mf][nf][rr];
      __syncthreads();
    } else {
      // v: scatter -> vt[ch][px]; then per-wave ctx MFMA over K=64 px
      #pragma unroll
      for (int mf = 0; mf < 2; ++mf)
        #pragma unroll
        for (int nf = 0; nf < 4; ++nf)
          #pragma unroll
          for (int rr = 0; rr < 4; ++rr)
            *(_Float16*)(vt + (mf * 16 + lg * 4 + rr) * 176 + (nf * 16 + ll) * 2) =
                (_Float16)acc[mf][nf][rr];
      __syncthreads();
      f32x4 ca[2][2] = {{fz, fz}, {fz, fz}};
      #pragma unroll
      for (int kk = 0; kk < 2; ++kk) {
        half8 a2[2], b2[2];
        #pragma unroll
        for (int ti = 0; ti < 2; ++ti) {
          a2[ti] = *(const half8*)(wt + (ti * 16 + ll) * 176 + kk * 64 + lg * 16);
          b2[ti] = *(const half8*)(vt + (ti * 16 + ll) * 176 + kk * 64 + lg * 16);
        }
        #pragma unroll
        for (int ti = 0; ti < 2; ++ti)
          #pragma unroll
          for (int tj = 0; tj < 2; ++tj)
            ca[ti][tj] = __builtin_amdgcn_mfma_f32_16x16x32_f16(a2[ti], b2[tj], ca[ti][tj], 0, 0, 0);
      }
      float* cb = ctx + (size_t)(b * 4 + w) * 1024;
      #pragma unroll
      for (int ti = 0; ti < 2; ++ti)
        #pragma unroll
        for (int tj = 0; tj < 2; ++tj)
          #pragma unroll
          for (int rr = 0; rr < 4; ++rr)
            atomicAdd(&cb[(ti * 16 + lg * 4 + rr) * 32 + tj * 16 + ll], ca[ti][tj][rr]);
    }
  }
}

// ---------------- k4b: M_h = W_out16[:,h*32..] @ (ctx^T * SCALE/sume), MFMA.
__global__ __launch_bounds__(256) void k4b_fold(const _Float16* __restrict__ Wo16,
                                                const float* __restrict__ ctx,
                                                const float* __restrict__ sumexp,
                                                _Float16* __restrict__ M) {
  const int mq = blockIdx.x, b = blockIdx.y;
  const int t = threadIdx.x;
  const int h = t >> 6, l = t & 63;
  const int m0 = mq * 64;
  const float* cb = ctx + (size_t)(b * 4 + h) * 1024;
  const float* sb = sumexp + b * 128 + h * 32;
  half8 bf[2];
  #pragma unroll
  for (int n0 = 0; n0 < 2; ++n0) {
    int d = n0 * 16 + (l & 15);
    float s = SCALE_F / sb[d];
    const float* ce = cb + d * 32 + (l >> 4) * 8;
    half8 hb;
    #pragma unroll
    for (int j = 0; j < 8; ++j) hb[j] = (_Float16)(ce[j] * s);
    bf[n0] = hb;
  }
  const f32x4 fz = {0.f, 0.f, 0.f, 0.f};
  _Float16* Mb = M + (size_t)(b * 256) * 128;
  #pragma unroll
  for (int mf = 0; mf < 4; ++mf) {
    int row = m0 + mf * 16 + (l & 15);
    half8 af = *(const half8*)(Wo16 + (size_t)row * 128 + h * 32 + (l >> 4) * 8);
    #pragma unroll
    for (int n0 = 0; n0 < 2; ++n0) {
      f32x4 c = __builtin_amdgcn_mfma_f32_16x16x32_f16(af, bf[n0], fz, 0, 0, 0);
      #pragma unroll
      for (int rr = 0; rr < 4; ++rr) {
        int r = m0 + mf * 16 + (l >> 4) * 4 + rr;
        Mb[(size_t)r * 128 + h * 32 + n0 * 16 + (l & 15)] = (_Float16)c[rr];
      }
    }
  }
}

// ---------------- k5: out = rmsnorm(M @ qhat + b_out, g_out), f32 ----------
__global__ __launch_bounds__(256) void k5c_out(const _Float16* __restrict__ M,
                                               const _Float16* __restrict__ qhat,
                                               const float* __restrict__ b_out,
                                               const float* __restrict__ g_out,
                                               float* __restrict__ out) {
  const int pt = blockIdx.x, b = blockIdx.y;
  const int p0 = pt * 64;
  const int t = threadIdx.x;
  const int wid = t >> 6, l = t & 63;
  __shared__ __align__(16) char smem[81920];
  float* rp = (float*)smem;                   // [256][68]
  float* bo = (float*)(smem + 69632);
  float* g16o = (float*)(smem + 70656);
  float* psum = (float*)(smem + 71680);
  float* sinvp = (float*)(smem + 72704);
  const _Float16* Mb = M + (size_t)b * 256 * 128;
  const _Float16* Qb = qhat + ((size_t)b * 4096 + p0) * 128;
  #pragma unroll
  for (int i = 0; i < 16; ++i) {
    int ci = t + 256 * i;
    int r = ci >> 4, c = ci & 15;
    *(half8*)(smem + r * 256 + ((c ^ (r & 15)) << 4)) = *(const half8*)(Mb + (size_t)r * 128 + c * 8);
  }
  #pragma unroll
  for (int i = 0; i < 4; ++i) {
    int ci = t + 256 * i;
    int r = ci >> 4, c = ci & 15;
    *(half8*)(smem + 65536 + r * 256 + ((c ^ (r & 15)) << 4)) = *(const half8*)(Qb + (size_t)r * 128 + c * 8);
  }
  __syncthreads();
  const f32x4 fz = {0.f, 0.f, 0.f, 0.f};
  f32x4 acc[4][4];
  #pragma unroll
  for (int i = 0; i < 4; ++i)
    #pragma unroll
    for (int j = 0; j < 4; ++j) acc[i][j] = fz;
  #pragma unroll
  for (int kk = 0; kk < 4; ++kk) {
    half8 af[4], bf[4];
    int ck = kk * 4 + (l >> 4);
    #pragma unroll
    for (int mf = 0; mf < 4; ++mf) {
      int r = wid * 64 + mf * 16 + (l & 15);
      af[mf] = *(const half8*)(smem + r * 256 + ((ck ^ (r & 15)) << 4));
    }
    #pragma unroll
    for (int nf = 0; nf < 4; ++nf) {
      int r = nf * 16 + (l & 15);
      bf[nf] = *(const half8*)(smem + 65536 + r * 256 + ((ck ^ (r & 15)) << 4));
    }
    #pragma unroll
    for (int mf = 0; mf < 4; ++mf)
      #pragma unroll
      for (int nf = 0; nf < 4; ++nf)
        acc[mf][nf] = __builtin_amdgcn_mfma_f32_16x16x32_f16(af[mf], bf[nf], acc[mf][nf], 0, 0, 0);
  }
  __syncthreads();
  bo[t] = b_out[t];
  g16o[t] = g_out[t] * 16.0f;
  #pragma unroll
  for (int mf = 0; mf < 4; ++mf)
    #pragma unroll
    for (int nf = 0; nf < 4; ++nf)
      #pragma unroll
      for (int rr = 0; rr < 4; ++rr) {
        int r = wid * 64 + mf * 16 + (l >> 4) * 4 + rr;
        int px = nf * 16 + (l & 15);
        rp[r * 68 + px] = acc[mf][nf][rr];
      }
  __syncthreads();
  {
    int px = t & 63, q = t >> 6;
    float s = 0.f;
    #pragma unroll
    for (int i = 0; i < 64; ++i) {
      int r = q * 64 + i;
      float f = rp[r * 68 + px] + bo[r];
      s += f * f;
    }
    psum[px * 4 + q] = s;
  }
  __syncthreads();
  if (t < 64)
    sinvp[t] = rsqrtf(psum[t * 4] + psum[t * 4 + 1] + psum[t * 4 + 2] + psum[t * 4 + 3] + 1e-12f);
  __syncthreads();
  float* ob = out + (size_t)(b * 256) * 4096 + p0;
  #pragma unroll
  for (int i = 0; i < 16; ++i) {
    int idx4 = t + 256 * i;
    int r = idx4 >> 4, px4 = (idx4 & 15) * 4;
    f32x4 v;
    #pragma unroll
    for (int ii = 0; ii < 4; ++ii)
      v[ii] = (rp[r * 68 + px4 + ii] + bo[r]) * sinvp[px4 + ii] * g16o[r];
    *(f32x4*)(ob + (size_t)r * 4096 + px4) = v;
  }
}

extern "C" void kernel_launch(void* const* d_in, const int* in_sizes, int n_in,
                              void* d_out, int out_size, void* d_ws, size_t ws_size,
                              hipStream_t stream) {
  const float* x      = (const float*)d_in[0];
  const float* W_qkv  = (const float*)d_in[1];
  const float* W_out  = (const float*)d_in[2];
  const float* b_out  = (const float*)d_in[3];
  const float* g_norm = (const float*)d_in[4];
  const float* g_out  = (const float*)d_in[5];
  float* out = (float*)d_out;
  char* ws = (char*)d_ws;
  if (ws_size < 51912704) return;

  _Float16* W16  = (_Float16*)(ws);
  _Float16* x_t  = (_Float16*)(ws + 196608);
  _Float16* qhat = (_Float16*)(ws + 33751040);
  float*    ctx  = (float*)(ws + 50528256);
  float*    sume = (float*)(ws + 50790400);
  _Float16* M    = (_Float16*)(ws + 50798592);
  _Float16* Wo16 = (_Float16*)(ws + 51847168);

  k1_prep<<<dim3(66, 16), 256, 0, stream>>>(x, g_norm, W_qkv, W_out, W16, Wo16, ctx, x_t);
  k2_fused<<<dim3(64, 16), 256, 0, stream>>>(W16, x_t, qhat, ctx, sume);
  k4b_fold<<<dim3(4, 16), 256, 0, stream>>>(Wo16, ctx, sume, M);
  k5c_out<<<dim3(64, 16), 256, 0, stream>>>(M, qhat, b_out, g_out, out);
}

// Round 5
// 97.185 us; speedup vs baseline: 1.0080x; 1.0080x over previous
//
#include <hip/hip_runtime.h>

// LinearAttention on MI355X (gfx950) — R5.
// R5 vs R4: k2 rebuilt: x-fragments in REGISTERS (loaded once, reused for
// q/k/v); W staged per-mt as one 64KB LDS tile with cross-mt prefetch under
// the epilogue; 512 threads (wave = head x px-half), px-tile 128; 9 barriers;
// ctx ph-halves combined in LDS before atomics.
// Workspace:
//   W16   fp16[384*256]        @ 0
//   x_t   fp16[16][4096][256]  @ 196608
//   qhat  fp16[16][4096][128]  @ 33751040
//   ctx   f32 [16][4][32][32]  @ 50528256
//   sume  f32 [16][128]        @ 50790400
//   M     fp16[16][256][128]   @ 50798592
//   Wo16  fp16[256*128]        @ 51847168  (ends 51912704)

typedef _Float16 half8 __attribute__((ext_vector_type(8)));
typedef _Float16 half4 __attribute__((ext_vector_type(4)));
typedef float f32x4 __attribute__((ext_vector_type(4)));

#define SCALE_F 0.17677669529663687f

#define GLOAD16(g, s) __builtin_amdgcn_global_load_lds( \
    (const __attribute__((address_space(1))) void*)(g), \
    (__attribute__((address_space(3))) void*)(s), 16, 0, 0)

// ---------------- k1: rmsnorm-fold + transpose x -> x_t fp16 [b][p][c];
// x==64: convert W_qkv + W_out to fp16; x==65: zero ctx+sume. ----
__global__ __launch_bounds__(256) void k1_prep(const float* __restrict__ x,
                                               const float* __restrict__ g_norm,
                                               const float* __restrict__ W_qkv,
                                               const float* __restrict__ W_out,
                                               _Float16* __restrict__ W16,
                                               _Float16* __restrict__ Wo16,
                                               float* __restrict__ zbase,
                                               _Float16* __restrict__ x_t) {
  const int t = threadIdx.x;
  if (blockIdx.x == 64) {              // W conversion: 16 blocks x 256 thr x 8
    #pragma unroll
    for (int i = 0; i < 8; ++i) {
      int idx = blockIdx.y * 2048 + i * 256 + t;   // 32768 f32x4 chunks
      f32x4 v;
      if (idx < 24576) v = *(const f32x4*)(W_qkv + (size_t)idx * 4);
      else             v = *(const f32x4*)(W_out + (size_t)(idx - 24576) * 4);
      half4 h = {(_Float16)v[0], (_Float16)v[1], (_Float16)v[2], (_Float16)v[3]};
      if (idx < 24576) *(half4*)(W16 + (size_t)idx * 4) = h;
      else             *(half4*)(Wo16 + (size_t)(idx - 24576) * 4) = h;
    }
    return;
  }
  if (blockIdx.x == 65) {              // zero ctx (256K) + sume (8K)
    const f32x4 fz = {0.f, 0.f, 0.f, 0.f};
    float* zb = zbase + blockIdx.y * 4224;
    for (int off = t * 4; off < 4224; off += 1024)
      *(f32x4*)(zb + off) = fz;
    return;
  }
  const int b = blockIdx.y;
  const int p0 = blockIdx.x * 64;
  __shared__ _Float16 tile[256][68];   // [ch][px]
  __shared__ float g16s[256];
  __shared__ float psum[64][4];
  __shared__ float sinv[64];
  g16s[t] = g_norm[t] * 16.0f;
  const float* xb = x + (size_t)b * 256 * 4096;
  #pragma unroll
  for (int it = 0; it < 16; ++it) {
    int c = it * 16 + (t >> 4);
    int px = (t & 15) * 4;
    f32x4 v = *(const f32x4*)(xb + (size_t)c * 4096 + p0 + px);
    half4 h = {(_Float16)v[0], (_Float16)v[1], (_Float16)v[2], (_Float16)v[3]};
    *(half4*)&tile[c][px] = h;
  }
  __syncthreads();
  {
    int px = t & 63, q = t >> 6;
    float s = 0.f;
    #pragma unroll
    for (int i = 0; i < 64; ++i) {
      float f = (float)tile[q * 64 + i][px];
      s += f * f;
    }
    psum[px][q] = s;
  }
  __syncthreads();
  if (t < 64) {
    float s = psum[t][0] + psum[t][1] + psum[t][2] + psum[t][3];
    sinv[t] = rsqrtf(s + 1e-12f);
  }
  __syncthreads();
  _Float16* xt = x_t + ((size_t)b * 4096 + p0) * 256;
  #pragma unroll
  for (int j = 0; j < 8; ++j) {
    int idx8 = t + 256 * j;
    int px = idx8 >> 5;
    int c8 = (idx8 & 31) * 8;
    float iv = sinv[px];
    half8 h;
    #pragma unroll
    for (int i = 0; i < 8; ++i)
      h[i] = (_Float16)((float)tile[c8 + i][px] * iv * g16s[c8 + i]);
    *(half8*)(xt + (size_t)px * 256 + c8) = h;
  }
}

// ---------------- k2_fused (R5): x-in-regs, W per-mt LDS, 512 thr ----------
// wave w: h = w>>1 (head), ph = w&1 (px half). px-tile 128.
// LDS: wbuf [128r][512B] swz (64KB) | wt [128ch][256B] swz (32KB, qt overlay)
//      vt overlays wbuf[0:32KB]; scr (f32[4][1024]) overlays wt after ctx.
__global__ __launch_bounds__(512) void k2_fused(const _Float16* __restrict__ W16,
                                                const _Float16* __restrict__ x_t,
                                                _Float16* __restrict__ qhat,
                                                float* __restrict__ ctx,
                                                float* __restrict__ sumexp) {
  const int pt = blockIdx.x, b = blockIdx.y;
  const int p0 = pt * 128;
  const int t = threadIdx.x;
  const int w = t >> 6, l = t & 63;
  const int h = w >> 1, ph = w & 1;
  const int lg = l >> 4, ll = l & 15;
  __shared__ __align__(1024) char smem[98304];
  char* wbuf = smem;
  char* wt = smem + 65536;
  char* vt = smem;
  float* scr = (float*)(smem + 65536);

  // ---- x fragments into registers (reused for all 3 mt) ----
  const _Float16* xrow = x_t + ((size_t)b * 4096 + p0 + ph * 64 + ll) * 256 + lg * 8;
  half8 bx[8][4];
  #pragma unroll
  for (int nf = 0; nf < 4; ++nf)
    #pragma unroll
    for (int kc = 0; kc < 8; ++kc)
      bx[kc][nf] = *(const half8*)(xrow + (size_t)nf * 16 * 256 + kc * 32);

  // ---- stage W(mt=0): 4096 16B chunks, pre-swizzled source ----
  #pragma unroll
  for (int i = 0; i < 8; ++i) {
    int q = (w * 8 + i) * 64 + l;
    int r = q >> 5, c = q & 31;
    GLOAD16(W16 + (size_t)r * 256 + (c ^ (r & 15)) * 8, smem + q * 16);
  }
  __syncthreads();

  const f32x4 fz = {0.f, 0.f, 0.f, 0.f};
  _Float16* qb = qhat + ((size_t)b * 4096 + p0) * 128;
  #pragma unroll
  for (int mt = 0; mt < 3; ++mt) {
    f32x4 acc[2][4];
    #pragma unroll
    for (int i = 0; i < 2; ++i)
      #pragma unroll
      for (int j = 0; j < 4; ++j) acc[i][j] = fz;
    #pragma unroll
    for (int ks = 0; ks < 8; ++ks) {
      half8 af[2];
      #pragma unroll
      for (int mf = 0; mf < 2; ++mf) {
        int r = h * 32 + mf * 16 + ll;
        af[mf] = *(const half8*)(wbuf + r * 512 + (((ks * 4 + lg) ^ ll) << 4));
      }
      #pragma unroll
      for (int mf = 0; mf < 2; ++mf)
        #pragma unroll
        for (int nf = 0; nf < 4; ++nf)
          acc[mf][nf] = __builtin_amdgcn_mfma_f32_16x16x32_f16(af[mf], bx[ks][nf], acc[mf][nf], 0, 0, 0);
    }
    __syncthreads();                       // all waves done reading wbuf
    if (mt < 2) {                          // prefetch next W under epilogue
      const _Float16* Wn = W16 + (size_t)(mt + 1) * 128 * 256;
      #pragma unroll
      for (int i = 0; i < 8; ++i) {
        int q = (w * 8 + i) * 64 + l;
        int r = q >> 5, c = q & 31;
        GLOAD16(Wn + (size_t)r * 256 + (c ^ (r & 15)) * 8, smem + q * 16);
      }
    }
    // acc value at (ch-in-head = mf*16 + lg*4 + rr, px-local = ph*64 + nf*16 + ll)
    if (mt == 0) {
      // q-softmax over head's 32 ch, in-register
      float s[4] = {0.f, 0.f, 0.f, 0.f};
      #pragma unroll
      for (int mf = 0; mf < 2; ++mf)
        #pragma unroll
        for (int nf = 0; nf < 4; ++nf)
          #pragma unroll
          for (int rr = 0; rr < 4; ++rr) {
            float v = __expf(acc[mf][nf][rr]);
            acc[mf][nf][rr] = v;
            s[nf] += v;
          }
      #pragma unroll
      for (int nf = 0; nf < 4; ++nf) {
        s[nf] += __shfl_xor(s[nf], 16);
        s[nf] += __shfl_xor(s[nf], 32);
        s[nf] = 1.0f / s[nf];
      }
      #pragma unroll
      for (int mf = 0; mf < 2; ++mf)
        #pragma unroll
        for (int nf = 0; nf < 4; ++nf)
          #pragma unroll
          for (int rr = 0; rr < 4; ++rr) {
            int p = ph * 64 + nf * 16 + ll;
            int cch = h * 32 + mf * 16 + lg * 4 + rr;
            *(_Float16*)(wt + p * 256 + (((cch >> 3) ^ (p & 15)) << 4) + (cch & 7) * 2) =
                (_Float16)(acc[mf][nf][rr] * s[nf]);
          }
      __syncthreads();                     // qt ready (also drains W1)
      #pragma unroll
      for (int i = 0; i < 4; ++i) {        // coalesced qhat store
        int q = (w * 4 + i) * 64 + l;
        int p = q >> 4, c16 = q & 15;
        half8 hv = *(const half8*)(wt + p * 256 + ((c16 ^ (p & 15)) << 4));
        *(half8*)(qb + (size_t)p * 128 + c16 * 8) = hv;
      }
    } else if (mt == 1) {
      // k: e = exp(logit-10); row-sums -> sume atomics; scatter -> wt
      float rs[2][4];
      #pragma unroll
      for (int mf = 0; mf < 2; ++mf)
        #pragma unroll
        for (int rr = 0; rr < 4; ++rr) rs[mf][rr] = 0.f;
      #pragma unroll
      for (int mf = 0; mf < 2; ++mf)
        #pragma unroll
        for (int nf = 0; nf < 4; ++nf)
          #pragma unroll
          for (int rr = 0; rr < 4; ++rr) {
            float v = __expf(acc[mf][nf][rr] - 10.f);
            acc[mf][nf][rr] = v;
            rs[mf][rr] += v;
          }
      #pragma unroll
      for (int mf = 0; mf < 2; ++mf)
        #pragma unroll
        for (int rr = 0; rr < 4; ++rr) {
          float v = rs[mf][rr];
          v += __shfl_xor(v, 1);
          v += __shfl_xor(v, 2);
          v += __shfl_xor(v, 4);
          v += __shfl_xor(v, 8);
          rs[mf][rr] = v;
        }
      if (ll == 0) {
        #pragma unroll
        for (int mf = 0; mf < 2; ++mf)
          #pragma unroll
          for (int rr = 0; rr < 4; ++rr)
            atomicAdd(&sumexp[b * 128 + h * 32 + mf * 16 + lg * 4 + rr], rs[mf][rr]);
      }
      #pragma unroll
      for (int mf = 0; mf < 2; ++mf)
        #pragma unroll
        for (int nf = 0; nf < 4; ++nf)
          #pragma unroll
          for (int rr = 0; rr < 4; ++rr) {
            int r = h * 32 + mf * 16 + lg * 4 + rr;
            int p = ph * 64 + nf * 16 + ll;
            *(_Float16*)(wt + r * 256 + (((p >> 3) ^ (r & 15)) << 4) + (p & 7) * 2) =
                (_Float16)acc[mf][nf][rr];
          }
      __syncthreads();                     // wt ready (also drains W2)
    } else {
      // v: scatter -> vt (overlays wbuf; safe after post-GEMM barrier)
      #pragma unroll
      for (int mf = 0; mf < 2; ++mf)
        #pragma unroll
        for (int nf = 0; nf < 4; ++nf)
          #pragma unroll
          for (int rr = 0; rr < 4; ++rr) {
            int r = h * 32 + mf * 16 + lg * 4 + rr;
            int p = ph * 64 + nf * 16 + ll;
            *(_Float16*)(vt + r * 256 + (((p >> 3) ^ (r & 15)) << 4) + (p & 7) * 2) =
                (_Float16)acc[mf][nf][rr];
          }
      __syncthreads();
      // ctx partial over this wave's px-half (K=64)
      f32x4 ca[2][2] = {{fz, fz}, {fz, fz}};
      #pragma unroll
      for (int ks2 = 0; ks2 < 2; ++ks2) {
        int cch = ph * 8 + ks2 * 4 + lg;
        half8 a2[2], b2[2];
        #pragma unroll
        for (int ti = 0; ti < 2; ++ti) {
          int ra = h * 32 + ti * 16 + ll;
          a2[ti] = *(const half8*)(wt + ra * 256 + ((cch ^ ll) << 4));
          b2[ti] = *(const half8*)(vt + ra * 256 + ((cch ^ ll) << 4));
        }
        #pragma unroll
        for (int ti = 0; ti < 2; ++ti)
          #pragma unroll
          for (int tj = 0; tj < 2; ++tj)
            ca[ti][tj] = __builtin_amdgcn_mfma_f32_16x16x32_f16(a2[ti], b2[tj], ca[ti][tj], 0, 0, 0);
      }
      __syncthreads();                     // wt reads done before scr overlay
      if (ph == 1) {
        #pragma unroll
        for (int ti = 0; ti < 2; ++ti)
          #pragma unroll
          for (int tj = 0; tj < 2; ++tj)
            #pragma unroll
            for (int rr = 0; rr < 4; ++rr)
              scr[h * 1024 + (ti * 16 + lg * 4 + rr) * 32 + tj * 16 + ll] = ca[ti][tj][rr];
      }
      __syncthreads();
      if (ph == 0) {
        float* cb = ctx + (size_t)(b * 4 + h) * 1024;
        #pragma unroll
        for (int ti = 0; ti < 2; ++ti)
          #pragma unroll
          for (int tj = 0; tj < 2; ++tj)
            #pragma unroll
            for (int rr = 0; rr < 4; ++rr) {
              int o = (ti * 16 + lg * 4 + rr) * 32 + tj * 16 + ll;
              atomicAdd(&cb[o], ca[ti][tj][rr] + scr[h * 1024 + o]);
            }
      }
    }
  }
}

// ---------------- k4b: M_h = W_out16[:,h*32..] @ (ctx^T * SCALE/sume), MFMA.
__global__ __launch_bounds__(256) void k4b_fold(const _Float16* __restrict__ Wo16,
                                                const float* __restrict__ ctx,
                                                const float* __restrict__ sumexp,
                                                _Float16* __restrict__ M) {
  const int mq = blockIdx.x, b = blockIdx.y;
  const int t = threadIdx.x;
  const int h = t >> 6, l = t & 63;
  const int m0 = mq * 64;
  const float* cb = ctx + (size_t)(b * 4 + h) * 1024;
  const float* sb = sumexp + b * 128 + h * 32;
  half8 bf[2];
  #pragma unroll
  for (int n0 = 0; n0 < 2; ++n0) {
    int d = n0 * 16 + (l & 15);
    float s = SCALE_F / sb[d];
    const float* ce = cb + d * 32 + (l >> 4) * 8;
    half8 hb;
    #pragma unroll
    for (int j = 0; j < 8; ++j) hb[j] = (_Float16)(ce[j] * s);
    bf[n0] = hb;
  }
  const f32x4 fz = {0.f, 0.f, 0.f, 0.f};
  _Float16* Mb = M + (size_t)(b * 256) * 128;
  #pragma unroll
  for (int mf = 0; mf < 4; ++mf) {
    int row = m0 + mf * 16 + (l & 15);
    half8 af = *(const half8*)(Wo16 + (size_t)row * 128 + h * 32 + (l >> 4) * 8);
    #pragma unroll
    for (int n0 = 0; n0 < 2; ++n0) {
      f32x4 c = __builtin_amdgcn_mfma_f32_16x16x32_f16(af, bf[n0], fz, 0, 0, 0);
      #pragma unroll
      for (int rr = 0; rr < 4; ++rr) {
        int r = m0 + mf * 16 + (l >> 4) * 4 + rr;
        Mb[(size_t)r * 128 + h * 32 + n0 * 16 + (l & 15)] = (_Float16)c[rr];
      }
    }
  }
}

// ---------------- k5: out = rmsnorm(M @ qhat + b_out, g_out), f32 ----------
__global__ __launch_bounds__(256) void k5c_out(const _Float16* __restrict__ M,
                                               const _Float16* __restrict__ qhat,
                                               const float* __restrict__ b_out,
                                               const float* __restrict__ g_out,
                                               float* __restrict__ out) {
  const int pt = blockIdx.x, b = blockIdx.y;
  const int p0 = pt * 64;
  const int t = threadIdx.x;
  const int wid = t >> 6, l = t & 63;
  __shared__ __align__(16) char smem[81920];
  float* rp = (float*)smem;                   // [256][68]
  float* bo = (float*)(smem + 69632);
  float* g16o = (float*)(smem + 70656);
  float* psum = (float*)(smem + 71680);
  float* sinvp = (float*)(smem + 72704);
  const _Float16* Mb = M + (size_t)b * 256 * 128;
  const _Float16* Qb = qhat + ((size_t)b * 4096 + p0) * 128;
  #pragma unroll
  for (int i = 0; i < 16; ++i) {
    int ci = t + 256 * i;
    int r = ci >> 4, c = ci & 15;
    *(half8*)(smem + r * 256 + ((c ^ (r & 15)) << 4)) = *(const half8*)(Mb + (size_t)r * 128 + c * 8);
  }
  #pragma unroll
  for (int i = 0; i < 4; ++i) {
    int ci = t + 256 * i;
    int r = ci >> 4, c = ci & 15;
    *(half8*)(smem + 65536 + r * 256 + ((c ^ (r & 15)) << 4)) = *(const half8*)(Qb + (size_t)r * 128 + c * 8);
  }
  __syncthreads();
  const f32x4 fz = {0.f, 0.f, 0.f, 0.f};
  f32x4 acc[4][4];
  #pragma unroll
  for (int i = 0; i < 4; ++i)
    #pragma unroll
    for (int j = 0; j < 4; ++j) acc[i][j] = fz;
  #pragma unroll
  for (int kk = 0; kk < 4; ++kk) {
    half8 af[4], bf[4];
    int ck = kk * 4 + (l >> 4);
    #pragma unroll
    for (int mf = 0; mf < 4; ++mf) {
      int r = wid * 64 + mf * 16 + (l & 15);
      af[mf] = *(const half8*)(smem + r * 256 + ((ck ^ (r & 15)) << 4));
    }
    #pragma unroll
    for (int nf = 0; nf < 4; ++nf) {
      int r = nf * 16 + (l & 15);
      bf[nf] = *(const half8*)(smem + 65536 + r * 256 + ((ck ^ (r & 15)) << 4));
    }
    #pragma unroll
    for (int mf = 0; mf < 4; ++mf)
      #pragma unroll
      for (int nf = 0; nf < 4; ++nf)
        acc[mf][nf] = __builtin_amdgcn_mfma_f32_16x16x32_f16(af[mf], bf[nf], acc[mf][nf], 0, 0, 0);
  }
  __syncthreads();
  bo[t] = b_out[t];
  g16o[t] = g_out[t] * 16.0f;
  #pragma unroll
  for (int mf = 0; mf < 4; ++mf)
    #pragma unroll
    for (int nf = 0; nf < 4; ++nf)
      #pragma unroll
      for (int rr = 0; rr < 4; ++rr) {
        int r = wid * 64 + mf * 16 + (l >> 4) * 4 + rr;
        int px = nf * 16 + (l & 15);
        rp[r * 68 + px] = acc[mf][nf][rr];
      }
  __syncthreads();
  {
    int px = t & 63, q = t >> 6;
    float s = 0.f;
    #pragma unroll
    for (int i = 0; i < 64; ++i) {
      int r = q * 64 + i;
      float f = rp[r * 68 + px] + bo[r];
      s += f * f;
    }
    psum[px * 4 + q] = s;
  }
  __syncthreads();
  if (t < 64)
    sinvp[t] = rsqrtf(psum[t * 4] + psum[t * 4 + 1] + psum[t * 4 + 2] + psum[t * 4 + 3] + 1e-12f);
  __syncthreads();
  float* ob = out + (size_t)(b * 256) * 4096 + p0;
  #pragma unroll
  for (int i = 0; i < 16; ++i) {
    int idx4 = t + 256 * i;
    int r = idx4 >> 4, px4 = (idx4 & 15) * 4;
    f32x4 v;
    #pragma unroll
    for (int ii = 0; ii < 4; ++ii)
      v[ii] = (rp[r * 68 + px4 + ii] + bo[r]) * sinvp[px4 + ii] * g16o[r];
    *(f32x4*)(ob + (size_t)r * 4096 + px4) = v;
  }
}

extern "C" void kernel_launch(void* const* d_in, const int* in_sizes, int n_in,
                              void* d_out, int out_size, void* d_ws, size_t ws_size,
                              hipStream_t stream) {
  const float* x      = (const float*)d_in[0];
  const float* W_qkv  = (const float*)d_in[1];
  const float* W_out  = (const float*)d_in[2];
  const float* b_out  = (const float*)d_in[3];
  const float* g_norm = (const float*)d_in[4];
  const float* g_out  = (const float*)d_in[5];
  float* out = (float*)d_out;
  char* ws = (char*)d_ws;
  if (ws_size < 51912704) return;

  _Float16* W16  = (_Float16*)(ws);
  _Float16* x_t  = (_Float16*)(ws + 196608);
  _Float16* qhat = (_Float16*)(ws + 33751040);
  float*    ctx  = (float*)(ws + 50528256);
  float*    sume = (float*)(ws + 50790400);
  _Float16* M    = (_Float16*)(ws + 50798592);
  _Float16* Wo16 = (_Float16*)(ws + 51847168);

  k1_prep<<<dim3(66, 16), 256, 0, stream>>>(x, g_norm, W_qkv, W_out, W16, Wo16, ctx, x_t);
  k2_fused<<<dim3(32, 16), 512, 0, stream>>>(W16, x_t, qhat, ctx, sume);
  k4b_fold<<<dim3(4, 16), 256, 0, stream>>>(Wo16, ctx, sume, M);
  k5c_out<<<dim3(64, 16), 256, 0, stream>>>(M, qhat, b_out, g_out, out);
}

// Round 6
// 92.073 us; speedup vs baseline: 1.0639x; 1.0555x over previous
//
#include <hip/hip_runtime.h>

// LinearAttention on MI355X (gfx950) — R6.
// R6 vs R5: k2: px-tile 64 / 256 thr / wave=head; x staged once in 32KB LDS;
// W fragments in REGISTERS (prefetched per-mt under epilogues, no W LDS, no
// W barriers); ALL atomics removed — per-block ctx/sume partials + k3_reduce.
// LDS 48KB -> up to 3 blocks/CU. Fully deterministic.
// Workspace:
//   W16   fp16[384*256]        @ 0
//   x_t   fp16[16][4096][256]  @ 196608
//   qhat  fp16[16][4096][128]  @ 33751040
//   ctx   f32 [16][4][32][32]  @ 50528256   (reduced)
//   sume  f32 [16][128]        @ 50790400   (reduced)
//   M     fp16[16][256][128]   @ 50798592
//   Wo16  fp16[256*128]        @ 51847168
//   ctxp  f32 [16][64][4][32][32] @ 51912704  (per-block partials)
//   sumep f32 [16][128][64]    @ 68689920   (ends 69214208)

typedef _Float16 half8 __attribute__((ext_vector_type(8)));
typedef _Float16 half4 __attribute__((ext_vector_type(4)));
typedef float f32x4 __attribute__((ext_vector_type(4)));

#define SCALE_F 0.17677669529663687f

#define GLOAD16(g, s) __builtin_amdgcn_global_load_lds( \
    (const __attribute__((address_space(1))) void*)(g), \
    (__attribute__((address_space(3))) void*)(s), 16, 0, 0)

// ---------------- k1: rmsnorm-fold + transpose x -> x_t fp16 [b][p][c];
// x==64: convert W_qkv + W_out to fp16. ----
__global__ __launch_bounds__(256) void k1_prep(const float* __restrict__ x,
                                               const float* __restrict__ g_norm,
                                               const float* __restrict__ W_qkv,
                                               const float* __restrict__ W_out,
                                               _Float16* __restrict__ W16,
                                               _Float16* __restrict__ Wo16,
                                               _Float16* __restrict__ x_t) {
  const int t = threadIdx.x;
  if (blockIdx.x == 64) {              // W conversion: 16 blocks x 256 thr x 8
    #pragma unroll
    for (int i = 0; i < 8; ++i) {
      int idx = blockIdx.y * 2048 + i * 256 + t;   // 32768 f32x4 chunks
      f32x4 v;
      if (idx < 24576) v = *(const f32x4*)(W_qkv + (size_t)idx * 4);
      else             v = *(const f32x4*)(W_out + (size_t)(idx - 24576) * 4);
      half4 h = {(_Float16)v[0], (_Float16)v[1], (_Float16)v[2], (_Float16)v[3]};
      if (idx < 24576) *(half4*)(W16 + (size_t)idx * 4) = h;
      else             *(half4*)(Wo16 + (size_t)(idx - 24576) * 4) = h;
    }
    return;
  }
  const int b = blockIdx.y;
  const int p0 = blockIdx.x * 64;
  __shared__ _Float16 tile[256][68];   // [ch][px]
  __shared__ float g16s[256];
  __shared__ float psum[64][4];
  __shared__ float sinv[64];
  g16s[t] = g_norm[t] * 16.0f;
  const float* xb = x + (size_t)b * 256 * 4096;
  #pragma unroll
  for (int it = 0; it < 16; ++it) {
    int c = it * 16 + (t >> 4);
    int px = (t & 15) * 4;
    f32x4 v = *(const f32x4*)(xb + (size_t)c * 4096 + p0 + px);
    half4 h = {(_Float16)v[0], (_Float16)v[1], (_Float16)v[2], (_Float16)v[3]};
    *(half4*)&tile[c][px] = h;
  }
  __syncthreads();
  {
    int px = t & 63, q = t >> 6;
    float s = 0.f;
    #pragma unroll
    for (int i = 0; i < 64; ++i) {
      float f = (float)tile[q * 64 + i][px];
      s += f * f;
    }
    psum[px][q] = s;
  }
  __syncthreads();
  if (t < 64) {
    float s = psum[t][0] + psum[t][1] + psum[t][2] + psum[t][3];
    sinv[t] = rsqrtf(s + 1e-12f);
  }
  __syncthreads();
  _Float16* xt = x_t + ((size_t)b * 4096 + p0) * 256;
  #pragma unroll
  for (int j = 0; j < 8; ++j) {
    int idx8 = t + 256 * j;
    int px = idx8 >> 5;
    int c8 = (idx8 & 31) * 8;
    float iv = sinv[px];
    half8 h;
    #pragma unroll
    for (int i = 0; i < 8; ++i)
      h[i] = (_Float16)((float)tile[c8 + i][px] * iv * g16s[c8 + i]);
    *(half8*)(xt + (size_t)px * 256 + c8) = h;
  }
}

// ---------------- k2_fused (R6): px-64, wave=head, W-in-regs, no atomics ----
__global__ __launch_bounds__(256, 3) void k2_fused(const _Float16* __restrict__ W16,
                                                   const _Float16* __restrict__ x_t,
                                                   _Float16* __restrict__ qhat,
                                                   float* __restrict__ ctxp,
                                                   float* __restrict__ sumep) {
  const int pt = blockIdx.x, b = blockIdx.y;
  const int p0 = pt * 64;
  const int t = threadIdx.x;
  const int h = t >> 6, l = t & 63;
  const int lg = l >> 4, ll = l & 15;
  __shared__ __align__(1024) char smem[49152];
  char* xbuf = smem;            // [64 px][512 B], swz: phys chunk holds logical c^(px&15)
  char* r2 = smem + 32768;      // 16 KB: qt (mt0) / wt (mt1..2)
  char* vt = smem;              // overlays xbuf after mt2 GEMM: [128 ch][128 B]

  // ---- stage x-tile once (2048 chunks, pre-swizzled source) ----
  const _Float16* Xbase = x_t + ((size_t)b * 4096 + p0) * 256;
  #pragma unroll
  for (int i = 0; i < 8; ++i) {
    int q = i * 256 + t;
    int px = q >> 5, c = q & 31;
    GLOAD16(Xbase + (size_t)px * 256 + (c ^ (px & 15)) * 8, smem + q * 16);
  }
  // ---- W fragments for mt=0 into registers (latency overlaps staging) ----
  half8 af[8][2];
  #pragma unroll
  for (int ks = 0; ks < 8; ++ks)
    #pragma unroll
    for (int mf = 0; mf < 2; ++mf)
      af[ks][mf] = *(const half8*)(W16 + (size_t)(h * 32 + mf * 16 + ll) * 256 + ks * 32 + lg * 8);
  __syncthreads();

  const f32x4 fz = {0.f, 0.f, 0.f, 0.f};
  #pragma unroll
  for (int mt = 0; mt < 3; ++mt) {
    f32x4 acc[2][4];
    #pragma unroll
    for (int i = 0; i < 2; ++i)
      #pragma unroll
      for (int j = 0; j < 4; ++j) acc[i][j] = fz;
    #pragma unroll
    for (int ks = 0; ks < 8; ++ks) {
      half8 bf[4];
      #pragma unroll
      for (int nf = 0; nf < 4; ++nf) {
        int px = nf * 16 + ll;
        bf[nf] = *(const half8*)(xbuf + px * 512 + (((ks * 4 + lg) ^ ll) << 4));
      }
      #pragma unroll
      for (int mf = 0; mf < 2; ++mf)
        #pragma unroll
        for (int nf = 0; nf < 4; ++nf)
          acc[mf][nf] = __builtin_amdgcn_mfma_f32_16x16x32_f16(af[ks][mf], bf[nf], acc[mf][nf], 0, 0, 0);
    }
    if (mt < 2) {   // prefetch next mt's W frags; consumed after epilogue
      const _Float16* Wn = W16 + (size_t)((mt + 1) * 128 + h * 32) * 256;
      #pragma unroll
      for (int ks = 0; ks < 8; ++ks)
        #pragma unroll
        for (int mf = 0; mf < 2; ++mf)
          af[ks][mf] = *(const half8*)(Wn + (size_t)(mf * 16 + ll) * 256 + ks * 32 + lg * 8);
    }
    // acc at (ch-in-head = mf*16 + lg*4 + rr, px = nf*16 + ll)
    if (mt == 0) {
      // q-softmax over head's 32 ch (in-register)
      float s[4] = {0.f, 0.f, 0.f, 0.f};
      #pragma unroll
      for (int mf = 0; mf < 2; ++mf)
        #pragma unroll
        for (int nf = 0; nf < 4; ++nf)
          #pragma unroll
          for (int rr = 0; rr < 4; ++rr) {
            float v = __expf(acc[mf][nf][rr]);
            acc[mf][nf][rr] = v;
            s[nf] += v;
          }
      #pragma unroll
      for (int nf = 0; nf < 4; ++nf) {
        s[nf] += __shfl_xor(s[nf], 16);
        s[nf] += __shfl_xor(s[nf], 32);
        s[nf] = 1.0f / s[nf];
      }
      #pragma unroll
      for (int mf = 0; mf < 2; ++mf)
        #pragma unroll
        for (int nf = 0; nf < 4; ++nf) {
          int px = nf * 16 + ll;
          int cphys = (h * 4 + mf * 2 + (lg >> 1)) ^ (px & 15);
          half4 hv;
          #pragma unroll
          for (int rr = 0; rr < 4; ++rr) hv[rr] = (_Float16)(acc[mf][nf][rr] * s[nf]);
          *(half4*)(r2 + px * 256 + (cphys << 4) + (lg & 1) * 8) = hv;
        }
      __syncthreads();
      _Float16* qb = qhat + ((size_t)b * 4096 + p0) * 128;
      #pragma unroll
      for (int i = 0; i < 4; ++i) {        // coalesced qhat store
        int q = i * 256 + t;
        int px = q >> 4, g = q & 15;
        half8 hv = *(const half8*)(r2 + px * 256 + ((g ^ (px & 15)) << 4));
        *(half8*)(qb + (size_t)px * 128 + g * 8) = hv;
      }
      __syncthreads();                     // qt reads done before wt reuse
    } else if (mt == 1) {
      // k: e = exp(logit-10); rowsum partials; scatter -> wt [ch][px]
      float rs[2][4];
      #pragma unroll
      for (int mf = 0; mf < 2; ++mf)
        #pragma unroll
        for (int rr = 0; rr < 4; ++rr) rs[mf][rr] = 0.f;
      #pragma unroll
      for (int mf = 0; mf < 2; ++mf)
        #pragma unroll
        for (int nf = 0; nf < 4; ++nf)
          #pragma unroll
          for (int rr = 0; rr < 4; ++rr) {
            float v = __expf(acc[mf][nf][rr] - 10.f);
            acc[mf][nf][rr] = v;
            rs[mf][rr] += v;
          }
      #pragma unroll
      for (int mf = 0; mf < 2; ++mf)
        #pragma unroll
        for (int rr = 0; rr < 4; ++rr) {
          float v = rs[mf][rr];
          v += __shfl_xor(v, 1);
          v += __shfl_xor(v, 2);
          v += __shfl_xor(v, 4);
          v += __shfl_xor(v, 8);
          rs[mf][rr] = v;
        }
      if (ll == 0) {
        #pragma unroll
        for (int mf = 0; mf < 2; ++mf)
          #pragma unroll
          for (int rr = 0; rr < 4; ++rr)
            sumep[((size_t)b * 128 + h * 32 + mf * 16 + lg * 4 + rr) * 64 + pt] = rs[mf][rr];
      }
      #pragma unroll
      for (int mf = 0; mf < 2; ++mf)
        #pragma unroll
        for (int nf = 0; nf < 4; ++nf)
          #pragma unroll
          for (int rr = 0; rr < 4; ++rr) {
            int ch = h * 32 + mf * 16 + lg * 4 + rr;
            int px = nf * 16 + ll;
            *(_Float16*)(r2 + ch * 128 + (((px >> 3) ^ (ch & 7)) << 4) + (px & 7) * 2) =
                (_Float16)acc[mf][nf][rr];
          }
      // no barrier: wt rows are read only by the wave that wrote them
    } else {
      __syncthreads();                     // all xbuf reads done before vt overlay
      #pragma unroll
      for (int mf = 0; mf < 2; ++mf)
        #pragma unroll
        for (int nf = 0; nf < 4; ++nf)
          #pragma unroll
          for (int rr = 0; rr < 4; ++rr) {
            int ch = h * 32 + mf * 16 + lg * 4 + rr;
            int px = nf * 16 + ll;
            *(_Float16*)(vt + ch * 128 + (((px >> 3) ^ (ch & 7)) << 4) + (px & 7) * 2) =
                (_Float16)acc[mf][nf][rr];
          }
      // PV: ctx_h[d][e] = sum_px w[d,px] v[e,px], K=64
      f32x4 ca[2][2] = {{fz, fz}, {fz, fz}};
      #pragma unroll
      for (int ks2 = 0; ks2 < 2; ++ks2) {
        half8 a2[2], b2[2];
        #pragma unroll
        for (int ti = 0; ti < 2; ++ti) {
          int ra = h * 32 + ti * 16 + ll;
          int cc = (ks2 * 4 + lg) ^ (ra & 7);
          a2[ti] = *(const half8*)(r2 + ra * 128 + (cc << 4));
          b2[ti] = *(const half8*)(vt + ra * 128 + (cc << 4));
        }
        #pragma unroll
        for (int ti = 0; ti < 2; ++ti)
          #pragma unroll
          for (int tj = 0; tj < 2; ++tj)
            ca[ti][tj] = __builtin_amdgcn_mfma_f32_16x16x32_f16(a2[ti], b2[tj], ca[ti][tj], 0, 0, 0);
      }
      float* cp = ctxp + (size_t)(((b * 64 + pt) * 4) + h) * 1024;
      #pragma unroll
      for (int ti = 0; ti < 2; ++ti)
        #pragma unroll
        for (int tj = 0; tj < 2; ++tj)
          #pragma unroll
          for (int rr = 0; rr < 4; ++rr)
            cp[(ti * 16 + lg * 4 + rr) * 32 + tj * 16 + ll] = ca[ti][tj][rr];
    }
  }
}

// ---------------- k3_reduce: fold ctxp/sumep partials -> ctx, sume ----------
__global__ __launch_bounds__(256) void k3_reduce(const float* __restrict__ ctxp,
                                                 const float* __restrict__ sumep,
                                                 float* __restrict__ ctx,
                                                 float* __restrict__ sume) {
  const int sl = blockIdx.x, b = blockIdx.y;
  const int t = threadIdx.x;
  if (sl == 0 && t < 128) {
    float s = 0.f;
    const float* sp = sumep + ((size_t)b * 128 + t) * 64;
    #pragma unroll 8
    for (int pt = 0; pt < 64; ++pt) s += sp[pt];
    sume[b * 128 + t] = s;
  }
  float a = 0.f;
  const float* p = ctxp + (size_t)b * 64 * 4096 + sl * 256 + t;
  #pragma unroll 8
  for (int pt = 0; pt < 64; ++pt) a += p[(size_t)pt * 4096];
  ctx[(size_t)b * 4096 + sl * 256 + t] = a;
}

// ---------------- k4b: M_h = W_out16[:,h*32..] @ (ctx^T * SCALE/sume), MFMA.
__global__ __launch_bounds__(256) void k4b_fold(const _Float16* __restrict__ Wo16,
                                                const float* __restrict__ ctx,
                                                const float* __restrict__ sumexp,
                                                _Float16* __restrict__ M) {
  const int mq = blockIdx.x, b = blockIdx.y;
  const int t = threadIdx.x;
  const int h = t >> 6, l = t & 63;
  const int m0 = mq * 64;
  const float* cb = ctx + (size_t)(b * 4 + h) * 1024;
  const float* sb = sumexp + b * 128 + h * 32;
  half8 bf[2];
  #pragma unroll
  for (int n0 = 0; n0 < 2; ++n0) {
    int d = n0 * 16 + (l & 15);
    float s = SCALE_F / sb[d];
    const float* ce = cb + d * 32 + (l >> 4) * 8;
    half8 hb;
    #pragma unroll
    for (int j = 0; j < 8; ++j) hb[j] = (_Float16)(ce[j] * s);
    bf[n0] = hb;
  }
  const f32x4 fz = {0.f, 0.f, 0.f, 0.f};
  _Float16* Mb = M + (size_t)(b * 256) * 128;
  #pragma unroll
  for (int mf = 0; mf < 4; ++mf) {
    int row = m0 + mf * 16 + (l & 15);
    half8 af = *(const half8*)(Wo16 + (size_t)row * 128 + h * 32 + (l >> 4) * 8);
    #pragma unroll
    for (int n0 = 0; n0 < 2; ++n0) {
      f32x4 c = __builtin_amdgcn_mfma_f32_16x16x32_f16(af, bf[n0], fz, 0, 0, 0);
      #pragma unroll
      for (int rr = 0; rr < 4; ++rr) {
        int r = m0 + mf * 16 + (l >> 4) * 4 + rr;
        Mb[(size_t)r * 128 + h * 32 + n0 * 16 + (l & 15)] = (_Float16)c[rr];
      }
    }
  }
}

// ---------------- k5: out = rmsnorm(M @ qhat + b_out, g_out), f32 ----------
__global__ __launch_bounds__(256) void k5c_out(const _Float16* __restrict__ M,
                                               const _Float16* __restrict__ qhat,
                                               const float* __restrict__ b_out,
                                               const float* __restrict__ g_out,
                                               float* __restrict__ out) {
  const int pt = blockIdx.x, b = blockIdx.y;
  const int p0 = pt * 64;
  const int t = threadIdx.x;
  const int wid = t >> 6, l = t & 63;
  __shared__ __align__(16) char smem[81920];
  float* rp = (float*)smem;                   // [256][68]
  float* bo = (float*)(smem + 69632);
  float* g16o = (float*)(smem + 70656);
  float* psum = (float*)(smem + 71680);
  float* sinvp = (float*)(smem + 72704);
  const _Float16* Mb = M + (size_t)b * 256 * 128;
  const _Float16* Qb = qhat + ((size_t)b * 4096 + p0) * 128;
  #pragma unroll
  for (int i = 0; i < 16; ++i) {
    int ci = t + 256 * i;
    int r = ci >> 4, c = ci & 15;
    *(half8*)(smem + r * 256 + ((c ^ (r & 15)) << 4)) = *(const half8*)(Mb + (size_t)r * 128 + c * 8);
  }
  #pragma unroll
  for (int i = 0; i < 4; ++i) {
    int ci = t + 256 * i;
    int r = ci >> 4, c = ci & 15;
    *(half8*)(smem + 65536 + r * 256 + ((c ^ (r & 15)) << 4)) = *(const half8*)(Qb + (size_t)r * 128 + c * 8);
  }
  __syncthreads();
  const f32x4 fz = {0.f, 0.f, 0.f, 0.f};
  f32x4 acc[4][4];
  #pragma unroll
  for (int i = 0; i < 4; ++i)
    #pragma unroll
    for (int j = 0; j < 4; ++j) acc[i][j] = fz;
  #pragma unroll
  for (int kk = 0; kk < 4; ++kk) {
    half8 af[4], bf[4];
    int ck = kk * 4 + (l >> 4);
    #pragma unroll
    for (int mf = 0; mf < 4; ++mf) {
      int r = wid * 64 + mf * 16 + (l & 15);
      af[mf] = *(const half8*)(smem + r * 256 + ((ck ^ (r & 15)) << 4));
    }
    #pragma unroll
    for (int nf = 0; nf < 4; ++nf) {
      int r = nf * 16 + (l & 15);
      bf[nf] = *(const half8*)(smem + 65536 + r * 256 + ((ck ^ (r & 15)) << 4));
    }
    #pragma unroll
    for (int mf = 0; mf < 4; ++mf)
      #pragma unroll
      for (int nf = 0; nf < 4; ++nf)
        acc[mf][nf] = __builtin_amdgcn_mfma_f32_16x16x32_f16(af[mf], bf[nf], acc[mf][nf], 0, 0, 0);
  }
  __syncthreads();
  bo[t] = b_out[t];
  g16o[t] = g_out[t] * 16.0f;
  #pragma unroll
  for (int mf = 0; mf < 4; ++mf)
    #pragma unroll
    for (int nf = 0; nf < 4; ++nf)
      #pragma unroll
      for (int rr = 0; rr < 4; ++rr) {
        int r = wid * 64 + mf * 16 + (l >> 4) * 4 + rr;
        int px = nf * 16 + (l & 15);
        rp[r * 68 + px] = acc[mf][nf][rr];
      }
  __syncthreads();
  {
    int px = t & 63, q = t >> 6;
    float s = 0.f;
    #pragma unroll
    for (int i = 0; i < 64; ++i) {
      int r = q * 64 + i;
      float f = rp[r * 68 + px] + bo[r];
      s += f * f;
    }
    psum[px * 4 + q] = s;
  }
  __syncthreads();
  if (t < 64)
    sinvp[t] = rsqrtf(psum[t * 4] + psum[t * 4 + 1] + psum[t * 4 + 2] + psum[t * 4 + 3] + 1e-12f);
  __syncthreads();
  float* ob = out + (size_t)(b * 256) * 4096 + p0;
  #pragma unroll
  for (int i = 0; i < 16; ++i) {
    int idx4 = t + 256 * i;
    int r = idx4 >> 4, px4 = (idx4 & 15) * 4;
    f32x4 v;
    #pragma unroll
    for (int ii = 0; ii < 4; ++ii)
      v[ii] = (rp[r * 68 + px4 + ii] + bo[r]) * sinvp[px4 + ii] * g16o[r];
    *(f32x4*)(ob + (size_t)r * 4096 + px4) = v;
  }
}

extern "C" void kernel_launch(void* const* d_in, const int* in_sizes, int n_in,
                              void* d_out, int out_size, void* d_ws, size_t ws_size,
                              hipStream_t stream) {
  const float* x      = (const float*)d_in[0];
  const float* W_qkv  = (const float*)d_in[1];
  const float* W_out  = (const float*)d_in[2];
  const float* b_out  = (const float*)d_in[3];
  const float* g_norm = (const float*)d_in[4];
  const float* g_out  = (const float*)d_in[5];
  float* out = (float*)d_out;
  char* ws = (char*)d_ws;
  if (ws_size < 69214208) return;

  _Float16* W16   = (_Float16*)(ws);
  _Float16* x_t   = (_Float16*)(ws + 196608);
  _Float16* qhat  = (_Float16*)(ws + 33751040);
  float*    ctx   = (float*)(ws + 50528256);
  float*    sume  = (float*)(ws + 50790400);
  _Float16* M     = (_Float16*)(ws + 50798592);
  _Float16* Wo16  = (_Float16*)(ws + 51847168);
  float*    ctxp  = (float*)(ws + 51912704);
  float*    sumep = (float*)(ws + 68689920);

  k1_prep<<<dim3(65, 16), 256, 0, stream>>>(x, g_norm, W_qkv, W_out, W16, Wo16, x_t);
  k2_fused<<<dim3(64, 16), 256, 0, stream>>>(W16, x_t, qhat, ctxp, sumep);
  k3_reduce<<<dim3(16, 16), 256, 0, stream>>>(ctxp, sumep, ctx, sume);
  k4b_fold<<<dim3(4, 16), 256, 0, stream>>>(Wo16, ctx, sume, M);
  k5c_out<<<dim3(64, 16), 256, 0, stream>>>(M, qhat, b_out, g_out, out);
}

// Round 7
// 80.187 us; speedup vs baseline: 1.2216x; 1.1482x over previous
//
#include <hip/hip_runtime.h>

// LinearAttention on MI355X (gfx950) — R7.
// R7 vs R6: x_t ELIMINATED. RMSNorm fused into k2_mega: g_norm*16 folded into
// W16 at convert time; raw x staged fp16 (same rounding as old k1); sinv[px]
// computed in-LDS and applied as per-column scalar in epilogues.
// 5 dispatches: kW(16) -> k2_mega(64x16) -> k3(16x16) -> k4b(4x16) -> k5(64x16).
// Workspace:
//   W16   fp16[384*256]  @ 0         (pre-scaled by g_norm*16)
//   Wo16  fp16[256*128]  @ 196608
//   qhat  fp16[16][4096][128] @ 262144
//   ctx   f32 [16][4096] @ 17039360
//   sume  f32 [16][128]  @ 17301504
//   M     fp16[16][256][128] @ 17309696
//   ctxp  f32 [16][64][4096] @ 18358272
//   sumep f32 [16][128][64]  @ 35135488  (ends 35659776)

typedef _Float16 half8 __attribute__((ext_vector_type(8)));
typedef _Float16 half4 __attribute__((ext_vector_type(4)));
typedef float f32x4 __attribute__((ext_vector_type(4)));

#define SCALE_F 0.17677669529663687f

#define GLOAD16(g, s) __builtin_amdgcn_global_load_lds( \
    (const __attribute__((address_space(1))) void*)(g), \
    (__attribute__((address_space(3))) void*)(s), 16, 0, 0)

// ---------------- kW: convert weights. W16 = W_qkv * g_norm*16 (per col). ---
__global__ __launch_bounds__(256) void kW(const float* __restrict__ W_qkv,
                                          const float* __restrict__ W_out,
                                          const float* __restrict__ g_norm,
                                          _Float16* __restrict__ W16,
                                          _Float16* __restrict__ Wo16) {
  const int t = threadIdx.x;
  __shared__ float g16s[256];
  g16s[t] = g_norm[t] * 16.0f;
  __syncthreads();
  #pragma unroll
  for (int i = 0; i < 8; ++i) {
    int idx = blockIdx.x * 2048 + i * 256 + t;   // 32768 f32x4 chunks total
    if (idx < 24576) {
      f32x4 v = *(const f32x4*)(W_qkv + (size_t)idx * 4);
      int c0 = (idx & 63) * 4;
      half4 h = {(_Float16)(v[0] * g16s[c0]), (_Float16)(v[1] * g16s[c0 + 1]),
                 (_Float16)(v[2] * g16s[c0 + 2]), (_Float16)(v[3] * g16s[c0 + 3])};
      *(half4*)(W16 + (size_t)idx * 4) = h;
    } else {
      f32x4 v = *(const f32x4*)(W_out + (size_t)(idx - 24576) * 4);
      half4 h = {(_Float16)v[0], (_Float16)v[1], (_Float16)v[2], (_Float16)v[3]};
      *(half4*)(Wo16 + (size_t)(idx - 24576) * 4) = h;
    }
  }
}

// ---------------- k2_mega: rmsnorm + QKV + q-softmax + k-exp + ctx ----------
// px-tile 64, 256 thr, wave = head. Raw-x fp16 staged transposed+swizzled;
// sinv applied in epilogues. No atomics (per-block partials).
__global__ __launch_bounds__(256, 3) void k2_mega(const _Float16* __restrict__ W16,
                                                  const float* __restrict__ x,
                                                  _Float16* __restrict__ qhat,
                                                  float* __restrict__ ctxp,
                                                  float* __restrict__ sumep) {
  const int pt = blockIdx.x, b = blockIdx.y;
  const int p0 = pt * 64;
  const int t = threadIdx.x;
  const int h = t >> 6, l = t & 63;
  const int lg = l >> 4, ll = l & 15;
  __shared__ __align__(1024) char smem[50432];
  char* xbuf = smem;            // [64 px][512 B] fp16 raw-x, chunk c at c^(px&15)
  char* r2 = smem + 32768;      // 16 KB: qt (mt0) / wt (mt1..2)
  char* vt = smem;              // overlays xbuf after mt2 GEMM
  float* psum = (float*)(smem + 49152);   // [64][4]
  float* sinvp = (float*)(smem + 50176);  // [64]

  // ---- stage raw x f32 -> fp16 transposed (swizzled scatter) ----
  const float* xb = x + ((size_t)b * 256) * 4096 + p0;
  #pragma unroll
  for (int it = 0; it < 16; ++it) {
    int ch = it * 16 + (t >> 4);
    int px4 = (t & 15) * 4;
    f32x4 v = *(const f32x4*)(xb + (size_t)ch * 4096 + px4);
    int c = ch >> 3, o = ch & 7;
    #pragma unroll
    for (int j = 0; j < 4; ++j) {
      int px = px4 + j;
      *(_Float16*)(xbuf + px * 512 + ((c ^ (px & 15)) << 4) + o * 2) = (_Float16)v[j];
    }
  }
  // ---- W fragments for mt=0 (global, independent of LDS) ----
  half8 af[8][2];
  #pragma unroll
  for (int ks = 0; ks < 8; ++ks)
    #pragma unroll
    for (int mf = 0; mf < 2; ++mf)
      af[ks][mf] = *(const half8*)(W16 + (size_t)(h * 32 + mf * 16 + ll) * 256 + ks * 32 + lg * 8);
  __syncthreads();
  // ---- rms sums: wave h sums ch quarter h for px = l ----
  {
    float s = 0.f;
    #pragma unroll
    for (int i = 0; i < 8; ++i) {
      int c = h * 8 + i;
      half8 hv = *(const half8*)(xbuf + l * 512 + ((c ^ (l & 15)) << 4));
      #pragma unroll
      for (int j = 0; j < 8; ++j) { float f = (float)hv[j]; s += f * f; }
    }
    psum[l * 4 + h] = s;
  }
  __syncthreads();
  if (t < 64)
    sinvp[t] = rsqrtf(psum[t * 4] + psum[t * 4 + 1] + psum[t * 4 + 2] + psum[t * 4 + 3] + 1e-12f);
  __syncthreads();
  float sv[4];
  #pragma unroll
  for (int nf = 0; nf < 4; ++nf) sv[nf] = sinvp[nf * 16 + ll];

  const f32x4 fz = {0.f, 0.f, 0.f, 0.f};
  #pragma unroll
  for (int mt = 0; mt < 3; ++mt) {
    f32x4 acc[2][4];
    #pragma unroll
    for (int i = 0; i < 2; ++i)
      #pragma unroll
      for (int j = 0; j < 4; ++j) acc[i][j] = fz;
    #pragma unroll
    for (int ks = 0; ks < 8; ++ks) {
      half8 bf[4];
      #pragma unroll
      for (int nf = 0; nf < 4; ++nf)
        bf[nf] = *(const half8*)(xbuf + (nf * 16 + ll) * 512 + (((ks * 4 + lg) ^ ll) << 4));
      #pragma unroll
      for (int mf = 0; mf < 2; ++mf)
        #pragma unroll
        for (int nf = 0; nf < 4; ++nf)
          acc[mf][nf] = __builtin_amdgcn_mfma_f32_16x16x32_f16(af[ks][mf], bf[nf], acc[mf][nf], 0, 0, 0);
    }
    if (mt < 2) {   // prefetch next mt's W frags; consumed after epilogue
      const _Float16* Wn = W16 + (size_t)((mt + 1) * 128 + h * 32) * 256;
      #pragma unroll
      for (int ks = 0; ks < 8; ++ks)
        #pragma unroll
        for (int mf = 0; mf < 2; ++mf)
          af[ks][mf] = *(const half8*)(Wn + (size_t)(mf * 16 + ll) * 256 + ks * 32 + lg * 8);
    }
    // acc at (ch-in-head = mf*16 + lg*4 + rr, px = nf*16 + ll); logit = acc*sv
    if (mt == 0) {
      // q-softmax over head's 32 ch (in-register)
      float s[4] = {0.f, 0.f, 0.f, 0.f};
      #pragma unroll
      for (int mf = 0; mf < 2; ++mf)
        #pragma unroll
        for (int nf = 0; nf < 4; ++nf)
          #pragma unroll
          for (int rr = 0; rr < 4; ++rr) {
            float v = __expf(acc[mf][nf][rr] * sv[nf]);
            acc[mf][nf][rr] = v;
            s[nf] += v;
          }
      #pragma unroll
      for (int nf = 0; nf < 4; ++nf) {
        s[nf] += __shfl_xor(s[nf], 16);
        s[nf] += __shfl_xor(s[nf], 32);
        s[nf] = 1.0f / s[nf];
      }
      #pragma unroll
      for (int mf = 0; mf < 2; ++mf)
        #pragma unroll
        for (int nf = 0; nf < 4; ++nf) {
          int px = nf * 16 + ll;
          int cphys = (h * 4 + mf * 2 + (lg >> 1)) ^ (px & 15);
          half4 hv;
          #pragma unroll
          for (int rr = 0; rr < 4; ++rr) hv[rr] = (_Float16)(acc[mf][nf][rr] * s[nf]);
          *(half4*)(r2 + px * 256 + (cphys << 4) + (lg & 1) * 8) = hv;
        }
      __syncthreads();
      _Float16* qb = qhat + ((size_t)b * 4096 + p0) * 128;
      #pragma unroll
      for (int i = 0; i < 4; ++i) {        // coalesced qhat store
        int q = i * 256 + t;
        int px = q >> 4, g = q & 15;
        half8 hv = *(const half8*)(r2 + px * 256 + ((g ^ (px & 15)) << 4));
        *(half8*)(qb + (size_t)px * 128 + g * 8) = hv;
      }
      __syncthreads();                     // qt reads done before wt reuse
    } else if (mt == 1) {
      // k: e = exp(sv*logit - 10); rowsum partials; scatter -> wt [ch][px]
      float rs[2][4];
      #pragma unroll
      for (int mf = 0; mf < 2; ++mf)
        #pragma unroll
        for (int rr = 0; rr < 4; ++rr) rs[mf][rr] = 0.f;
      #pragma unroll
      for (int mf = 0; mf < 2; ++mf)
        #pragma unroll
        for (int nf = 0; nf < 4; ++nf)
          #pragma unroll
          for (int rr = 0; rr < 4; ++rr) {
            float v = __expf(acc[mf][nf][rr] * sv[nf] - 10.f);
            acc[mf][nf][rr] = v;
            rs[mf][rr] += v;
          }
      #pragma unroll
      for (int mf = 0; mf < 2; ++mf)
        #pragma unroll
        for (int rr = 0; rr < 4; ++rr) {
          float v = rs[mf][rr];
          v += __shfl_xor(v, 1);
          v += __shfl_xor(v, 2);
          v += __shfl_xor(v, 4);
          v += __shfl_xor(v, 8);
          rs[mf][rr] = v;
        }
      if (ll == 0) {
        #pragma unroll
        for (int mf = 0; mf < 2; ++mf)
          #pragma unroll
          for (int rr = 0; rr < 4; ++rr)
            sumep[((size_t)b * 128 + h * 32 + mf * 16 + lg * 4 + rr) * 64 + pt] = rs[mf][rr];
      }
      #pragma unroll
      for (int mf = 0; mf < 2; ++mf)
        #pragma unroll
        for (int nf = 0; nf < 4; ++nf)
          #pragma unroll
          for (int rr = 0; rr < 4; ++rr) {
            int ch = h * 32 + mf * 16 + lg * 4 + rr;
            int px = nf * 16 + ll;
            *(_Float16*)(r2 + ch * 128 + (((px >> 3) ^ (ch & 7)) << 4) + (px & 7) * 2) =
                (_Float16)acc[mf][nf][rr];
          }
      // no barrier: wt rows read only by the wave that wrote them
    } else {
      __syncthreads();                     // all xbuf reads done before vt overlay
      #pragma unroll
      for (int mf = 0; mf < 2; ++mf)
        #pragma unroll
        for (int nf = 0; nf < 4; ++nf)
          #pragma unroll
          for (int rr = 0; rr < 4; ++rr) {
            int ch = h * 32 + mf * 16 + lg * 4 + rr;
            int px = nf * 16 + ll;
            *(_Float16*)(vt + ch * 128 + (((px >> 3) ^ (ch & 7)) << 4) + (px & 7) * 2) =
                (_Float16)(acc[mf][nf][rr] * sv[nf]);
          }
      // PV: ctx_h[d][e] = sum_px w[d,px] v[e,px], K=64
      f32x4 ca[2][2] = {{fz, fz}, {fz, fz}};
      #pragma unroll
      for (int ks2 = 0; ks2 < 2; ++ks2) {
        half8 a2[2], b2[2];
        #pragma unroll
        for (int ti = 0; ti < 2; ++ti) {
          int ra = h * 32 + ti * 16 + ll;
          int cc = (ks2 * 4 + lg) ^ (ra & 7);
          a2[ti] = *(const half8*)(r2 + ra * 128 + (cc << 4));
          b2[ti] = *(const half8*)(vt + ra * 128 + (cc << 4));
        }
        #pragma unroll
        for (int ti = 0; ti < 2; ++ti)
          #pragma unroll
          for (int tj = 0; tj < 2; ++tj)
            ca[ti][tj] = __builtin_amdgcn_mfma_f32_16x16x32_f16(a2[ti], b2[tj], ca[ti][tj], 0, 0, 0);
      }
      float* cp = ctxp + (size_t)(((b * 64 + pt) * 4) + h) * 1024;
      #pragma unroll
      for (int ti = 0; ti < 2; ++ti)
        #pragma unroll
        for (int tj = 0; tj < 2; ++tj)
          #pragma unroll
          for (int rr = 0; rr < 4; ++rr)
            cp[(ti * 16 + lg * 4 + rr) * 32 + tj * 16 + ll] = ca[ti][tj][rr];
    }
  }
}

// ---------------- k3_reduce: fold ctxp/sumep partials -> ctx, sume ----------
__global__ __launch_bounds__(256) void k3_reduce(const float* __restrict__ ctxp,
                                                 const float* __restrict__ sumep,
                                                 float* __restrict__ ctx,
                                                 float* __restrict__ sume) {
  const int sl = blockIdx.x, b = blockIdx.y;
  const int t = threadIdx.x;
  if (sl == 0 && t < 128) {
    float s = 0.f;
    const float* sp = sumep + ((size_t)b * 128 + t) * 64;
    #pragma unroll 8
    for (int pt = 0; pt < 64; ++pt) s += sp[pt];
    sume[b * 128 + t] = s;
  }
  float a = 0.f;
  const float* p = ctxp + (size_t)b * 64 * 4096 + sl * 256 + t;
  #pragma unroll 8
  for (int pt = 0; pt < 64; ++pt) a += p[(size_t)pt * 4096];
  ctx[(size_t)b * 4096 + sl * 256 + t] = a;
}

// ---------------- k4b: M_h = W_out16[:,h*32..] @ (ctx^T * SCALE/sume), MFMA.
__global__ __launch_bounds__(256) void k4b_fold(const _Float16* __restrict__ Wo16,
                                                const float* __restrict__ ctx,
                                                const float* __restrict__ sumexp,
                                                _Float16* __restrict__ M) {
  const int mq = blockIdx.x, b = blockIdx.y;
  const int t = threadIdx.x;
  const int h = t >> 6, l = t & 63;
  const int m0 = mq * 64;
  const float* cb = ctx + (size_t)(b * 4 + h) * 1024;
  const float* sb = sumexp + b * 128 + h * 32;
  half8 bf[2];
  #pragma unroll
  for (int n0 = 0; n0 < 2; ++n0) {
    int d = n0 * 16 + (l & 15);
    float s = SCALE_F / sb[d];
    const float* ce = cb + d * 32 + (l >> 4) * 8;
    half8 hb;
    #pragma unroll
    for (int j = 0; j < 8; ++j) hb[j] = (_Float16)(ce[j] * s);
    bf[n0] = hb;
  }
  const f32x4 fz = {0.f, 0.f, 0.f, 0.f};
  _Float16* Mb = M + (size_t)(b * 256) * 128;
  #pragma unroll
  for (int mf = 0; mf < 4; ++mf) {
    int row = m0 + mf * 16 + (l & 15);
    half8 af = *(const half8*)(Wo16 + (size_t)row * 128 + h * 32 + (l >> 4) * 8);
    #pragma unroll
    for (int n0 = 0; n0 < 2; ++n0) {
      f32x4 c = __builtin_amdgcn_mfma_f32_16x16x32_f16(af, bf[n0], fz, 0, 0, 0);
      #pragma unroll
      for (int rr = 0; rr < 4; ++rr) {
        int r = m0 + mf * 16 + (l >> 4) * 4 + rr;
        Mb[(size_t)r * 128 + h * 32 + n0 * 16 + (l & 15)] = (_Float16)c[rr];
      }
    }
  }
}

// ---------------- k5: out = rmsnorm(M @ qhat + b_out, g_out), f32 ----------
__global__ __launch_bounds__(256) void k5c_out(const _Float16* __restrict__ M,
                                               const _Float16* __restrict__ qhat,
                                               const float* __restrict__ b_out,
                                               const float* __restrict__ g_out,
                                               float* __restrict__ out) {
  const int pt = blockIdx.x, b = blockIdx.y;
  const int p0 = pt * 64;
  const int t = threadIdx.x;
  const int wid = t >> 6, l = t & 63;
  __shared__ __align__(16) char smem[81920];
  float* rp = (float*)smem;                   // [256][68]
  float* bo = (float*)(smem + 69632);
  float* g16o = (float*)(smem + 70656);
  float* psum = (float*)(smem + 71680);
  float* sinvp = (float*)(smem + 72704);
  const _Float16* Mb = M + (size_t)b * 256 * 128;
  const _Float16* Qb = qhat + ((size_t)b * 4096 + p0) * 128;
  #pragma unroll
  for (int i = 0; i < 16; ++i) {
    int ci = t + 256 * i;
    int r = ci >> 4, c = ci & 15;
    *(half8*)(smem + r * 256 + ((c ^ (r & 15)) << 4)) = *(const half8*)(Mb + (size_t)r * 128 + c * 8);
  }
  #pragma unroll
  for (int i = 0; i < 4; ++i) {
    int ci = t + 256 * i;
    int r = ci >> 4, c = ci & 15;
    *(half8*)(smem + 65536 + r * 256 + ((c ^ (r & 15)) << 4)) = *(const half8*)(Qb + (size_t)r * 128 + c * 8);
  }
  __syncthreads();
  const f32x4 fz = {0.f, 0.f, 0.f, 0.f};
  f32x4 acc[4][4];
  #pragma unroll
  for (int i = 0; i < 4; ++i)
    #pragma unroll
    for (int j = 0; j < 4; ++j) acc[i][j] = fz;
  #pragma unroll
  for (int kk = 0; kk < 4; ++kk) {
    half8 af[4], bf[4];
    int ck = kk * 4 + (l >> 4);
    #pragma unroll
    for (int mf = 0; mf < 4; ++mf) {
      int r = wid * 64 + mf * 16 + (l & 15);
      af[mf] = *(const half8*)(smem + r * 256 + ((ck ^ (r & 15)) << 4));
    }
    #pragma unroll
    for (int nf = 0; nf < 4; ++nf) {
      int r = nf * 16 + (l & 15);
      bf[nf] = *(const half8*)(smem + 65536 + r * 256 + ((ck ^ (r & 15)) << 4));
    }
    #pragma unroll
    for (int mf = 0; mf < 4; ++mf)
      #pragma unroll
      for (int nf = 0; nf < 4; ++nf)
        acc[mf][nf] = __builtin_amdgcn_mfma_f32_16x16x32_f16(af[mf], bf[nf], acc[mf][nf], 0, 0, 0);
  }
  __syncthreads();
  bo[t] = b_out[t];
  g16o[t] = g_out[t] * 16.0f;
  #pragma unroll
  for (int mf = 0; mf < 4; ++mf)
    #pragma unroll
    for (int nf = 0; nf < 4; ++nf)
      #pragma unroll
      for (int rr = 0; rr < 4; ++rr) {
        int r = wid * 64 + mf * 16 + (l >> 4) * 4 + rr;
        int px = nf * 16 + (l & 15);
        rp[r * 68 + px] = acc[mf][nf][rr];
      }
  __syncthreads();
  {
    int px = t & 63, q = t >> 6;
    float s = 0.f;
    #pragma unroll
    for (int i = 0; i < 64; ++i) {
      int r = q * 64 + i;
      float f = rp[r * 68 + px] + bo[r];
      s += f * f;
    }
    psum[px * 4 + q] = s;
  }
  __syncthreads();
  if (t < 64)
    sinvp[t] = rsqrtf(psum[t * 4] + psum[t * 4 + 1] + psum[t * 4 + 2] + psum[t * 4 + 3] + 1e-12f);
  __syncthreads();
  float* ob = out + (size_t)(b * 256) * 4096 + p0;
  #pragma unroll
  for (int i = 0; i < 16; ++i) {
    int idx4 = t + 256 * i;
    int r = idx4 >> 4, px4 = (idx4 & 15) * 4;
    f32x4 v;
    #pragma unroll
    for (int ii = 0; ii < 4; ++ii)
      v[ii] = (rp[r * 68 + px4 + ii] + bo[r]) * sinvp[px4 + ii] * g16o[r];
    *(f32x4*)(ob + (size_t)r * 4096 + px4) = v;
  }
}

extern "C" void kernel_launch(void* const* d_in, const int* in_sizes, int n_in,
                              void* d_out, int out_size, void* d_ws, size_t ws_size,
                              hipStream_t stream) {
  const float* x      = (const float*)d_in[0];
  const float* W_qkv  = (const float*)d_in[1];
  const float* W_out  = (const float*)d_in[2];
  const float* b_out  = (const float*)d_in[3];
  const float* g_norm = (const float*)d_in[4];
  const float* g_out  = (const float*)d_in[5];
  float* out = (float*)d_out;
  char* ws = (char*)d_ws;
  if (ws_size < 35659776) return;

  _Float16* W16   = (_Float16*)(ws);
  _Float16* Wo16  = (_Float16*)(ws + 196608);
  _Float16* qhat  = (_Float16*)(ws + 262144);
  float*    ctx   = (float*)(ws + 17039360);
  float*    sume  = (float*)(ws + 17301504);
  _Float16* M     = (_Float16*)(ws + 17309696);
  float*    ctxp  = (float*)(ws + 18358272);
  float*    sumep = (float*)(ws + 35135488);

  kW<<<16, 256, 0, stream>>>(W_qkv, W_out, g_norm, W16, Wo16);
  k2_mega<<<dim3(64, 16), 256, 0, stream>>>(W16, x, qhat, ctxp, sumep);
  k3_reduce<<<dim3(16, 16), 256, 0, stream>>>(ctxp, sumep, ctx, sume);
  k4b_fold<<<dim3(4, 16), 256, 0, stream>>>(Wo16, ctx, sume, M);
  k5c_out<<<dim3(64, 16), 256, 0, stream>>>(M, qhat, b_out, g_out, out);
}

// Round 8
// 76.560 us; speedup vs baseline: 1.2795x; 1.0474x over previous
//
#include <hip/hip_runtime.h>

// LinearAttention on MI355X (gfx950) — R8.
// R8 vs R7: k2_mega staging rewritten. Thread (h,l) owns px=l and 4
// consecutive channels per iteration: 4 coalesced f32 loads -> half4 -> ONE
// 8B LDS write (was 64 scalar 2B scatters). RMS sum accumulated in-register
// during staging (no column re-reads). Swizzle key extended with
// ((px>>4)&1)<<4 on both sides: write conflicts 4-way -> 2-way (free).
// Workspace:
//   W16   fp16[384*256]  @ 0         (pre-scaled by g_norm*16)
//   Wo16  fp16[256*128]  @ 196608
//   qhat  fp16[16][4096][128] @ 262144
//   ctx   f32 [16][4096] @ 17039360
//   sume  f32 [16][128]  @ 17301504
//   M     fp16[16][256][128] @ 17309696
//   ctxp  f32 [16][64][4096] @ 18358272
//   sumep f32 [16][128][64]  @ 35135488  (ends 35659776)

typedef _Float16 half8 __attribute__((ext_vector_type(8)));
typedef _Float16 half4 __attribute__((ext_vector_type(4)));
typedef float f32x4 __attribute__((ext_vector_type(4)));

#define SCALE_F 0.17677669529663687f

// ---------------- kW: convert weights. W16 = W_qkv * g_norm*16 (per col). ---
__global__ __launch_bounds__(256) void kW(const float* __restrict__ W_qkv,
                                          const float* __restrict__ W_out,
                                          const float* __restrict__ g_norm,
                                          _Float16* __restrict__ W16,
                                          _Float16* __restrict__ Wo16) {
  const int t = threadIdx.x;
  __shared__ float g16s[256];
  g16s[t] = g_norm[t] * 16.0f;
  __syncthreads();
  #pragma unroll
  for (int i = 0; i < 8; ++i) {
    int idx = blockIdx.x * 2048 + i * 256 + t;   // 32768 f32x4 chunks total
    if (idx < 24576) {
      f32x4 v = *(const f32x4*)(W_qkv + (size_t)idx * 4);
      int c0 = (idx & 63) * 4;
      half4 h = {(_Float16)(v[0] * g16s[c0]), (_Float16)(v[1] * g16s[c0 + 1]),
                 (_Float16)(v[2] * g16s[c0 + 2]), (_Float16)(v[3] * g16s[c0 + 3])};
      *(half4*)(W16 + (size_t)idx * 4) = h;
    } else {
      f32x4 v = *(const f32x4*)(W_out + (size_t)(idx - 24576) * 4);
      half4 h = {(_Float16)v[0], (_Float16)v[1], (_Float16)v[2], (_Float16)v[3]};
      *(half4*)(Wo16 + (size_t)(idx - 24576) * 4) = h;
    }
  }
}

// ---------------- k2_mega: rmsnorm + QKV + q-softmax + k-exp + ctx ----------
// px-tile 64, 256 thr, wave = head. Thread (h,l): px=l, 4 ch/iter staging.
__global__ __launch_bounds__(256, 3) void k2_mega(const _Float16* __restrict__ W16,
                                                  const float* __restrict__ x,
                                                  _Float16* __restrict__ qhat,
                                                  float* __restrict__ ctxp,
                                                  float* __restrict__ sumep) {
  const int pt = blockIdx.x, b = blockIdx.y;
  const int p0 = pt * 64;
  const int t = threadIdx.x;
  const int h = t >> 6, l = t & 63;
  const int lg = l >> 4, ll = l & 15;
  __shared__ __align__(1024) char smem[50432];
  char* xbuf = smem;            // [64 px][512 B] fp16, chunk c at c^key(px),
                                // key(px) = (px&15) | ((px>>4)&1)<<4
  char* r2 = smem + 32768;      // 16 KB: qt (mt0) / wt (mt1..2)
  char* vt = smem;              // overlays xbuf after mt2 GEMM
  float* psum = (float*)(smem + 49152);   // [64][4]
  float* sinvp = (float*)(smem + 50176);  // [64]

  // ---- stage raw x: px=l, 4 consecutive ch per iter; rms in-register ----
  {
    const float* xb = x + ((size_t)b * 256) * 4096 + p0 + l;
    float rsum = 0.f;
    #pragma unroll
    for (int it = 0; it < 16; ++it) {
      int ch0 = it * 16 + h * 4;
      const float* xc = xb + (size_t)ch0 * 4096;
      float v0 = xc[0];
      float v1 = xc[4096];
      float v2 = xc[8192];
      float v3 = xc[12288];
      half4 hv = {(_Float16)v0, (_Float16)v1, (_Float16)v2, (_Float16)v3};
      #pragma unroll
      for (int j = 0; j < 4; ++j) { float f = (float)hv[j]; rsum += f * f; }
      int c = it * 2 + (h >> 1);
      int swz = c ^ (l & 15) ^ (((l >> 4) & 1) << 4);
      *(half4*)(xbuf + l * 512 + (swz << 4) + (h & 1) * 8) = hv;
    }
    psum[l * 4 + h] = rsum;
  }
  // ---- W fragments for mt=0 (global, independent of LDS) ----
  half8 af[8][2];
  #pragma unroll
  for (int ks = 0; ks < 8; ++ks)
    #pragma unroll
    for (int mf = 0; mf < 2; ++mf)
      af[ks][mf] = *(const half8*)(W16 + (size_t)(h * 32 + mf * 16 + ll) * 256 + ks * 32 + lg * 8);
  __syncthreads();
  if (t < 64)
    sinvp[t] = rsqrtf(psum[t * 4] + psum[t * 4 + 1] + psum[t * 4 + 2] + psum[t * 4 + 3] + 1e-12f);
  __syncthreads();
  float sv[4];
  #pragma unroll
  for (int nf = 0; nf < 4; ++nf) sv[nf] = sinvp[nf * 16 + ll];

  const f32x4 fz = {0.f, 0.f, 0.f, 0.f};
  #pragma unroll
  for (int mt = 0; mt < 3; ++mt) {
    f32x4 acc[2][4];
    #pragma unroll
    for (int i = 0; i < 2; ++i)
      #pragma unroll
      for (int j = 0; j < 4; ++j) acc[i][j] = fz;
    #pragma unroll
    for (int ks = 0; ks < 8; ++ks) {
      half8 bf[4];
      #pragma unroll
      for (int nf = 0; nf < 4; ++nf)
        bf[nf] = *(const half8*)(xbuf + (nf * 16 + ll) * 512 +
                                 ((((ks * 4 + lg) ^ ll) ^ ((nf & 1) << 4)) << 4));
      #pragma unroll
      for (int mf = 0; mf < 2; ++mf)
        #pragma unroll
        for (int nf = 0; nf < 4; ++nf)
          acc[mf][nf] = __builtin_amdgcn_mfma_f32_16x16x32_f16(af[ks][mf], bf[nf], acc[mf][nf], 0, 0, 0);
    }
    if (mt < 2) {   // prefetch next mt's W frags; consumed after epilogue
      const _Float16* Wn = W16 + (size_t)((mt + 1) * 128 + h * 32) * 256;
      #pragma unroll
      for (int ks = 0; ks < 8; ++ks)
        #pragma unroll
        for (int mf = 0; mf < 2; ++mf)
          af[ks][mf] = *(const half8*)(Wn + (size_t)(mf * 16 + ll) * 256 + ks * 32 + lg * 8);
    }
    // acc at (ch-in-head = mf*16 + lg*4 + rr, px = nf*16 + ll); logit = acc*sv
    if (mt == 0) {
      // q-softmax over head's 32 ch (in-register)
      float s[4] = {0.f, 0.f, 0.f, 0.f};
      #pragma unroll
      for (int mf = 0; mf < 2; ++mf)
        #pragma unroll
        for (int nf = 0; nf < 4; ++nf)
          #pragma unroll
          for (int rr = 0; rr < 4; ++rr) {
            float v = __expf(acc[mf][nf][rr] * sv[nf]);
            acc[mf][nf][rr] = v;
            s[nf] += v;
          }
      #pragma unroll
      for (int nf = 0; nf < 4; ++nf) {
        s[nf] += __shfl_xor(s[nf], 16);
        s[nf] += __shfl_xor(s[nf], 32);
        s[nf] = 1.0f / s[nf];
      }
      #pragma unroll
      for (int mf = 0; mf < 2; ++mf)
        #pragma unroll
        for (int nf = 0; nf < 4; ++nf) {
          int px = nf * 16 + ll;
          int cphys = (h * 4 + mf * 2 + (lg >> 1)) ^ (px & 15);
          half4 hv;
          #pragma unroll
          for (int rr = 0; rr < 4; ++rr) hv[rr] = (_Float16)(acc[mf][nf][rr] * s[nf]);
          *(half4*)(r2 + px * 256 + (cphys << 4) + (lg & 1) * 8) = hv;
        }
      __syncthreads();
      _Float16* qb = qhat + ((size_t)b * 4096 + p0) * 128;
      #pragma unroll
      for (int i = 0; i < 4; ++i) {        // coalesced qhat store
        int q = i * 256 + t;
        int px = q >> 4, g = q & 15;
        half8 hv = *(const half8*)(r2 + px * 256 + ((g ^ (px & 15)) << 4));
        *(half8*)(qb + (size_t)px * 128 + g * 8) = hv;
      }
      __syncthreads();                     // qt reads done before wt reuse
    } else if (mt == 1) {
      // k: e = exp(sv*logit - 10); rowsum partials; scatter -> wt [ch][px]
      float rs[2][4];
      #pragma unroll
      for (int mf = 0; mf < 2; ++mf)
        #pragma unroll
        for (int rr = 0; rr < 4; ++rr) rs[mf][rr] = 0.f;
      #pragma unroll
      for (int mf = 0; mf < 2; ++mf)
        #pragma unroll
        for (int nf = 0; nf < 4; ++nf)
          #pragma unroll
          for (int rr = 0; rr < 4; ++rr) {
            float v = __expf(acc[mf][nf][rr] * sv[nf] - 10.f);
            acc[mf][nf][rr] = v;
            rs[mf][rr] += v;
          }
      #pragma unroll
      for (int mf = 0; mf < 2; ++mf)
        #pragma unroll
        for (int rr = 0; rr < 4; ++rr) {
          float v = rs[mf][rr];
          v += __shfl_xor(v, 1);
          v += __shfl_xor(v, 2);
          v += __shfl_xor(v, 4);
          v += __shfl_xor(v, 8);
          rs[mf][rr] = v;
        }
      if (ll == 0) {
        #pragma unroll
        for (int mf = 0; mf < 2; ++mf)
          #pragma unroll
          for (int rr = 0; rr < 4; ++rr)
            sumep[((size_t)b * 128 + h * 32 + mf * 16 + lg * 4 + rr) * 64 + pt] = rs[mf][rr];
      }
      #pragma unroll
      for (int mf = 0; mf < 2; ++mf)
        #pragma unroll
        for (int nf = 0; nf < 4; ++nf)
          #pragma unroll
          for (int rr = 0; rr < 4; ++rr) {
            int ch = h * 32 + mf * 16 + lg * 4 + rr;
            int px = nf * 16 + ll;
            *(_Float16*)(r2 + ch * 128 + (((px >> 3) ^ (ch & 7)) << 4) + (px & 7) * 2) =
                (_Float16)acc[mf][nf][rr];
          }
      // no barrier: wt rows read only by the wave that wrote them
    } else {
      __syncthreads();                     // all xbuf reads done before vt overlay
      #pragma unroll
      for (int mf = 0; mf < 2; ++mf)
        #pragma unroll
        for (int nf = 0; nf < 4; ++nf)
          #pragma unroll
          for (int rr = 0; rr < 4; ++rr) {
            int ch = h * 32 + mf * 16 + lg * 4 + rr;
            int px = nf * 16 + ll;
            *(_Float16*)(vt + ch * 128 + (((px >> 3) ^ (ch & 7)) << 4) + (px & 7) * 2) =
                (_Float16)(acc[mf][nf][rr] * sv[nf]);
          }
      // PV: ctx_h[d][e] = sum_px w[d,px] v[e,px], K=64
      f32x4 ca[2][2] = {{fz, fz}, {fz, fz}};
      #pragma unroll
      for (int ks2 = 0; ks2 < 2; ++ks2) {
        half8 a2[2], b2[2];
        #pragma unroll
        for (int ti = 0; ti < 2; ++ti) {
          int ra = h * 32 + ti * 16 + ll;
          int cc = (ks2 * 4 + lg) ^ (ra & 7);
          a2[ti] = *(const half8*)(r2 + ra * 128 + (cc << 4));
          b2[ti] = *(const half8*)(vt + ra * 128 + (cc << 4));
        }
        #pragma unroll
        for (int ti = 0; ti < 2; ++ti)
          #pragma unroll
          for (int tj = 0; tj < 2; ++tj)
            ca[ti][tj] = __builtin_amdgcn_mfma_f32_16x16x32_f16(a2[ti], b2[tj], ca[ti][tj], 0, 0, 0);
      }
      float* cp = ctxp + (size_t)(((b * 64 + pt) * 4) + h) * 1024;
      #pragma unroll
      for (int ti = 0; ti < 2; ++ti)
        #pragma unroll
        for (int tj = 0; tj < 2; ++tj)
          #pragma unroll
          for (int rr = 0; rr < 4; ++rr)
            cp[(ti * 16 + lg * 4 + rr) * 32 + tj * 16 + ll] = ca[ti][tj][rr];
    }
  }
}

// ---------------- k3_reduce: fold ctxp/sumep partials -> ctx, sume ----------
__global__ __launch_bounds__(256) void k3_reduce(const float* __restrict__ ctxp,
                                                 const float* __restrict__ sumep,
                                                 float* __restrict__ ctx,
                                                 float* __restrict__ sume) {
  const int sl = blockIdx.x, b = blockIdx.y;
  const int t = threadIdx.x;
  if (sl == 0 && t < 128) {
    float s = 0.f;
    const float* sp = sumep + ((size_t)b * 128 + t) * 64;
    #pragma unroll 8
    for (int pt = 0; pt < 64; ++pt) s += sp[pt];
    sume[b * 128 + t] = s;
  }
  float a = 0.f;
  const float* p = ctxp + (size_t)b * 64 * 4096 + sl * 256 + t;
  #pragma unroll 8
  for (int pt = 0; pt < 64; ++pt) a += p[(size_t)pt * 4096];
  ctx[(size_t)b * 4096 + sl * 256 + t] = a;
}

// ---------------- k4b: M_h = W_out16[:,h*32..] @ (ctx^T * SCALE/sume), MFMA.
__global__ __launch_bounds__(256) void k4b_fold(const _Float16* __restrict__ Wo16,
                                                const float* __restrict__ ctx,
                                                const float* __restrict__ sumexp,
                                                _Float16* __restrict__ M) {
  const int mq = blockIdx.x, b = blockIdx.y;
  const int t = threadIdx.x;
  const int h = t >> 6, l = t & 63;
  const int m0 = mq * 64;
  const float* cb = ctx + (size_t)(b * 4 + h) * 1024;
  const float* sb = sumexp + b * 128 + h * 32;
  half8 bf[2];
  #pragma unroll
  for (int n0 = 0; n0 < 2; ++n0) {
    int d = n0 * 16 + (l & 15);
    float s = SCALE_F / sb[d];
    const float* ce = cb + d * 32 + (l >> 4) * 8;
    half8 hb;
    #pragma unroll
    for (int j = 0; j < 8; ++j) hb[j] = (_Float16)(ce[j] * s);
    bf[n0] = hb;
  }
  const f32x4 fz = {0.f, 0.f, 0.f, 0.f};
  _Float16* Mb = M + (size_t)(b * 256) * 128;
  #pragma unroll
  for (int mf = 0; mf < 4; ++mf) {
    int row = m0 + mf * 16 + (l & 15);
    half8 af = *(const half8*)(Wo16 + (size_t)row * 128 + h * 32 + (l >> 4) * 8);
    #pragma unroll
    for (int n0 = 0; n0 < 2; ++n0) {
      f32x4 c = __builtin_amdgcn_mfma_f32_16x16x32_f16(af, bf[n0], fz, 0, 0, 0);
      #pragma unroll
      for (int rr = 0; rr < 4; ++rr) {
        int r = m0 + mf * 16 + (l >> 4) * 4 + rr;
        Mb[(size_t)r * 128 + h * 32 + n0 * 16 + (l & 15)] = (_Float16)c[rr];
      }
    }
  }
}

// ---------------- k5: out = rmsnorm(M @ qhat + b_out, g_out), f32 ----------
__global__ __launch_bounds__(256) void k5c_out(const _Float16* __restrict__ M,
                                               const _Float16* __restrict__ qhat,
                                               const float* __restrict__ b_out,
                                               const float* __restrict__ g_out,
                                               float* __restrict__ out) {
  const int pt = blockIdx.x, b = blockIdx.y;
  const int p0 = pt * 64;
  const int t = threadIdx.x;
  const int wid = t >> 6, l = t & 63;
  __shared__ __align__(16) char smem[81920];
  float* rp = (float*)smem;                   // [256][68]
  float* bo = (float*)(smem + 69632);
  float* g16o = (float*)(smem + 70656);
  float* psum = (float*)(smem + 71680);
  float* sinvp = (float*)(smem + 72704);
  const _Float16* Mb = M + (size_t)b * 256 * 128;
  const _Float16* Qb = qhat + ((size_t)b * 4096 + p0) * 128;
  #pragma unroll
  for (int i = 0; i < 16; ++i) {
    int ci = t + 256 * i;
    int r = ci >> 4, c = ci & 15;
    *(half8*)(smem + r * 256 + ((c ^ (r & 15)) << 4)) = *(const half8*)(Mb + (size_t)r * 128 + c * 8);
  }
  #pragma unroll
  for (int i = 0; i < 4; ++i) {
    int ci = t + 256 * i;
    int r = ci >> 4, c = ci & 15;
    *(half8*)(smem + 65536 + r * 256 + ((c ^ (r & 15)) << 4)) = *(const half8*)(Qb + (size_t)r * 128 + c * 8);
  }
  __syncthreads();
  const f32x4 fz = {0.f, 0.f, 0.f, 0.f};
  f32x4 acc[4][4];
  #pragma unroll
  for (int i = 0; i < 4; ++i)
    #pragma unroll
    for (int j = 0; j < 4; ++j) acc[i][j] = fz;
  #pragma unroll
  for (int kk = 0; kk < 4; ++kk) {
    half8 af[4], bf[4];
    int ck = kk * 4 + (l >> 4);
    #pragma unroll
    for (int mf = 0; mf < 4; ++mf) {
      int r = wid * 64 + mf * 16 + (l & 15);
      af[mf] = *(const half8*)(smem + r * 256 + ((ck ^ (r & 15)) << 4));
    }
    #pragma unroll
    for (int nf = 0; nf < 4; ++nf) {
      int r = nf * 16 + (l & 15);
      bf[nf] = *(const half8*)(smem + 65536 + r * 256 + ((ck ^ (r & 15)) << 4));
    }
    #pragma unroll
    for (int mf = 0; mf < 4; ++mf)
      #pragma unroll
      for (int nf = 0; nf < 4; ++nf)
        acc[mf][nf] = __builtin_amdgcn_mfma_f32_16x16x32_f16(af[mf], bf[nf], acc[mf][nf], 0, 0, 0);
  }
  __syncthreads();
  bo[t] = b_out[t];
  g16o[t] = g_out[t] * 16.0f;
  #pragma unroll
  for (int mf = 0; mf < 4; ++mf)
    #pragma unroll
    for (int nf = 0; nf < 4; ++nf)
      #pragma unroll
      for (int rr = 0; rr < 4; ++rr) {
        int r = wid * 64 + mf * 16 + (l >> 4) * 4 + rr;
        int px = nf * 16 + (l & 15);
        rp[r * 68 + px] = acc[mf][nf][rr];
      }
  __syncthreads();
  {
    int px = t & 63, q = t >> 6;
    float s = 0.f;
    #pragma unroll
    for (int i = 0; i < 64; ++i) {
      int r = q * 64 + i;
      float f = rp[r * 68 + px] + bo[r];
      s += f * f;
    }
    psum[px * 4 + q] = s;
  }
  __syncthreads();
  if (t < 64)
    sinvp[t] = rsqrtf(psum[t * 4] + psum[t * 4 + 1] + psum[t * 4 + 2] + psum[t * 4 + 3] + 1e-12f);
  __syncthreads();
  float* ob = out + (size_t)(b * 256) * 4096 + p0;
  #pragma unroll
  for (int i = 0; i < 16; ++i) {
    int idx4 = t + 256 * i;
    int r = idx4 >> 4, px4 = (idx4 & 15) * 4;
    f32x4 v;
    #pragma unroll
    for (int ii = 0; ii < 4; ++ii)
      v[ii] = (rp[r * 68 + px4 + ii] + bo[r]) * sinvp[px4 + ii] * g16o[r];
    *(f32x4*)(ob + (size_t)r * 4096 + px4) = v;
  }
}

extern "C" void kernel_launch(void* const* d_in, const int* in_sizes, int n_in,
                              void* d_out, int out_size, void* d_ws, size_t ws_size,
                              hipStream_t stream) {
  const float* x      = (const float*)d_in[0];
  const float* W_qkv  = (const float*)d_in[1];
  const float* W_out  = (const float*)d_in[2];
  const float* b_out  = (const float*)d_in[3];
  const float* g_norm = (const float*)d_in[4];
  const float* g_out  = (const float*)d_in[5];
  float* out = (float*)d_out;
  char* ws = (char*)d_ws;
  if (ws_size < 35659776) return;

  _Float16* W16   = (_Float16*)(ws);
  _Float16* Wo16  = (_Float16*)(ws + 196608);
  _Float16* qhat  = (_Float16*)(ws + 262144);
  float*    ctx   = (float*)(ws + 17039360);
  float*    sume  = (float*)(ws + 17301504);
  _Float16* M     = (_Float16*)(ws + 17309696);
  float*    ctxp  = (float*)(ws + 18358272);
  float*    sumep = (float*)(ws + 35135488);

  kW<<<16, 256, 0, stream>>>(W_qkv, W_out, g_norm, W16, Wo16);
  k2_mega<<<dim3(64, 16), 256, 0, stream>>>(W16, x, qhat, ctxp, sumep);
  k3_reduce<<<dim3(16, 16), 256, 0, stream>>>(ctxp, sumep, ctx, sume);
  k4b_fold<<<dim3(4, 16), 256, 0, stream>>>(Wo16, ctx, sume, M);
  k5c_out<<<dim3(64, 16), 256, 0, stream>>>(M, qhat, b_out, g_out, out);
}